// Round 9
// baseline (533.829 us; speedup 1.0000x reference)
//
#include <hip/hip_runtime.h>
#include <hip/hip_bf16.h>
#include <cstdint>
#include <cstddef>

typedef __attribute__((ext_vector_type(8))) short short8;
typedef __attribute__((ext_vector_type(4))) float f32x4;

#define DEVI static __device__ __forceinline__

DEVI unsigned short f2bf(float f) {
  unsigned u = __float_as_uint(f);
  unsigned r = u + 0x7fffu + ((u >> 16) & 1u);
  return (unsigned short)(r >> 16);
}
DEVI float bf2f(unsigned short s) {
  return __uint_as_float(((unsigned)s) << 16);
}
DEVI unsigned pack2(float a, float b) {
  return (unsigned)f2bf(a) | ((unsigned)f2bf(b) << 16);
}

DEVI void gload16(const void* g, void* l) {
  __builtin_amdgcn_global_load_lds(
      (__attribute__((address_space(1))) void*)g,
      (__attribute__((address_space(3))) void*)l, 16, 0, 0);
}

// ---------------------------------------------------------------------------
// prep_w: wcat bf16 [768][256] with PERMUTED rows:
//   rows 0..255   = Wq
//   rows 256+     = K/V head-pairs interleaved:
//     for hp in 0..3: 64 K-rows (heads 2hp,2hp+1) then 64 V-rows (same heads)
// wpb bf16 [256][256] = Wproj.
// ---------------------------------------------------------------------------
__global__ __launch_bounds__(256) void prep_w(
    const float* __restrict__ Wq, const float* __restrict__ Wkv,
    const float* __restrict__ Wp, unsigned short* __restrict__ wcat,
    unsigned short* __restrict__ wpb) {
  int i = blockIdx.x * 256 + threadIdx.x;  // grid 1024 -> 262144 exact
  if (i < 196608) {
    int R = i >> 8, col = i & 255;
    float v;
    if (R < 256) {
      v = Wq[R * 256 + col];
    } else {
      int g = R - 256;
      int hp = g >> 7, rem = g & 127;
      int kvrow = (rem < 64) ? (hp * 64 + rem) : (256 + hp * 64 + (rem - 64));
      v = Wkv[kvrow * 256 + col];
    }
    wcat[i] = f2bf(v);
  } else {
    int j = i - 196608;
    wpb[j] = f2bf(Wp[j]);
  }
}

// ---------------------------------------------------------------------------
// qkv_ctx v2: 512 blocks (2/CU exactly) x 256 thr (4 waves), 4 panels of
// 64 rows each. Per panel: x->bf16 LDS (conflict-free slots), A-frags cached
// in REGISTERS (af[4][8]); 12 W-slivers (64 cols) double-buffered gload_lds:
//   s 0..3  : Q (elu, block-wide bounce -> coalesced 128B stores)
//   s 4,6,8,10: K head-pair (elu -> kT transposed; ksum via shfl)
//   s 5,7,9,11: V head-pair (-> vT); then ctx MFMA into REGISTER cacc
// Block epilogue: pctx[blk][8][32][32] fp32 + pksum[blk][8][32].
// LDS 80KB: wb0(32K) wb1(32K) kT(8K) vT(8K).
// ---------------------------------------------------------------------------
__global__ __launch_bounds__(256, 2) void qkv_ctx(
    const float* __restrict__ x, const unsigned short* __restrict__ wcat,
    unsigned short* __restrict__ Q, float* __restrict__ pctx,
    float* __restrict__ pksum) {
  const int t = threadIdx.x;
  const int lane = t & 63, w = t >> 6;
  const int fr = lane & 15, fq = lane >> 4;
  const int blk = blockIdx.x;

  __shared__ __align__(16) unsigned char smem[81920];
  unsigned char* const wb0 = smem;
  unsigned char* const wb1 = smem + 32768;
  unsigned char* const kT = smem + 65536;
  unsigned char* const vT = smem + 73728;

  f32x4 cacc[4][2];
  float ksr[4] = {0.f, 0.f, 0.f, 0.f};
#pragma unroll
  for (int p = 0; p < 4; ++p)
#pragma unroll
    for (int dp = 0; dp < 2; ++dp)
#pragma unroll
      for (int c = 0; c < 4; ++c) cacc[p][dp][c] = 0.f;

  const int segr = lane >> 5;
  const int segc = (lane & 31) * 16;

  auto stage_w = [&](unsigned char* buf, int sl) {
#pragma unroll
    for (int i = 0; i < 8; ++i) {
      int seg = w * 8 + i;
      int rloc = seg * 2 + segr;
      gload16((const char*)wcat + (size_t)(sl * 64 + rloc) * 512 +
                  (segc ^ ((rloc & 7) << 4)),
              buf + seg * 1024);
    }
  };

  for (int pp = 0; pp < 4; ++pp) {
    const size_t prow0 = (size_t)blk * 256 + (size_t)pp * 64;

    // ---- stage x panel -> wb1 (bf16, bank-conflict-free slot bijection) ----
    {
      const int r = t >> 2, qt = t & 3;
      const float* xrow = x + (prow0 + r) * 256;
      unsigned char* drow = wb1 + r * 512;
      const int swz = (r & 7) << 4;
#pragma unroll
      for (int i = 0; i < 8; ++i) {
        float4 a = *(const float4*)(xrow + i * 32 + qt * 8);
        float4 b2 = *(const float4*)(xrow + i * 32 + qt * 8 + 4);
        uint4 u;
        u.x = pack2(a.x, a.y);
        u.y = pack2(a.z, a.w);
        u.z = pack2(b2.x, b2.y);
        u.w = pack2(b2.z, b2.w);
        int slot = (i >> 1) * 8 + qt * 2 + (i & 1);  // sigma(c), c = i*4+qt
        *(uint4*)(drow + ((slot * 16) ^ swz)) = u;
      }
    }
    stage_w(wb0, 0);
    __syncthreads();

    // ---- A-fragments into registers: af[i2][ks], rows i2*16+fr ----
    short8 af[4][8];
#pragma unroll
    for (int i2 = 0; i2 < 4; ++i2) {
      const int ra = i2 * 16 + fr;
      const unsigned char* arow = wb1 + ra * 512;
      const int swz = (ra & 7) << 4;
#pragma unroll
      for (int ks = 0; ks < 8; ++ks) {
        int slot = (ks >> 1) * 8 + fq * 2 + (ks & 1);  // sigma(ks*4+fq)
        af[i2][ks] = *(const short8*)(arow + ((slot * 16) ^ swz));
      }
    }
    __syncthreads();  // af in regs; wb1 free for staging

#pragma unroll
    for (int s = 0; s < 12; ++s) {
      if (s < 11) stage_w(((s & 1) == 0) ? wb1 : wb0, s + 1);
      const unsigned char* wbuf = ((s & 1) == 0) ? wb0 : wb1;

      f32x4 acc[4] = {{0.f, 0.f, 0.f, 0.f},
                      {0.f, 0.f, 0.f, 0.f},
                      {0.f, 0.f, 0.f, 0.f},
                      {0.f, 0.f, 0.f, 0.f}};
      const int rb = w * 16 + fr;
      const int swb = (rb & 7) << 4;
#pragma unroll
      for (int ks = 0; ks < 8; ++ks) {
        short8 bf8 =
            *(const short8*)(wbuf + rb * 512 + ((ks * 64 + fq * 16) ^ swb));
#pragma unroll
        for (int i2 = 0; i2 < 4; ++i2)
          acc[i2] = __builtin_amdgcn_mfma_f32_16x16x32_bf16(af[i2][ks], bf8,
                                                            acc[i2], 0, 0, 0);
      }

      if (s < 4) {
        // ---- Q sliver: elu, block-wide bounce (kT area), coalesced store ----
#pragma unroll
        for (int i2 = 0; i2 < 4; ++i2)
#pragma unroll
          for (int reg = 0; reg < 4; ++reg) {
            int row = i2 * 16 + fq * 4 + reg;
            float v = acc[i2][reg];
            v = (v > 0.f) ? (v + 1.f) : __expf(v);
            *(unsigned short*)(kT + row * 128 +
                               (((w * 16 + fr) * 2) ^ ((row & 7) << 4))) =
                f2bf(v);
          }
        __syncthreads();
#pragma unroll
        for (int it = 0; it < 2; ++it) {
          int idx = t + it * 256;
          int row = idx >> 3, j = idx & 7;
          uint4 u =
              *(const uint4*)(kT + row * 128 + ((j * 16) ^ ((row & 7) << 4)));
          *(uint4*)((char*)Q + (prow0 + row) * 512 + s * 128 + j * 16) = u;
        }
      } else if (((s - 4) & 1) == 0) {
        // ---- K sliver (pair p): elu -> kT transposed; ksum partial ----
        const int p = (s - 4) >> 1;
        const int d = (w & 1) * 16 + fr;
        const int swd = (d & 7) << 4;
        unsigned char* kbase = kT + (w >> 1) * 4096 + d * 128;
        float part = 0.f;
#pragma unroll
        for (int i2 = 0; i2 < 4; ++i2)
#pragma unroll
          for (int reg = 0; reg < 4; ++reg) {
            int n = i2 * 16 + fq * 4 + reg;
            float v = acc[i2][reg];
            v = (v > 0.f) ? (v + 1.f) : __expf(v);
            part += v;
            *(unsigned short*)(kbase + ((n * 2) ^ swd)) = f2bf(v);
          }
        part += __shfl_xor(part, 16, 64);
        part += __shfl_xor(part, 32, 64);
        ksr[p] += part;
      } else {
        // ---- V sliver (pair p): -> vT; then ctx MFMA into registers ----
        const int p = (s - 4) >> 1;
        const int d = (w & 1) * 16 + fr;
        const int swd = (d & 7) << 4;
        unsigned char* vbase = vT + (w >> 1) * 4096 + d * 128;
#pragma unroll
        for (int i2 = 0; i2 < 4; ++i2)
#pragma unroll
          for (int reg = 0; reg < 4; ++reg) {
            int n = i2 * 16 + fq * 4 + reg;
            *(unsigned short*)(vbase + ((n * 2) ^ swd)) = f2bf(acc[i2][reg]);
          }
        __syncthreads();
        const int ev = (w & 1) * 16 + fr;
        const int swe = (ev & 7) << 4;
#pragma unroll
        for (int ks = 0; ks < 2; ++ks) {
          short8 bv = *(const short8*)(vT + (w >> 1) * 4096 + ev * 128 +
                                       ((ks * 64 + fq * 16) ^ swe));
#pragma unroll
          for (int dp = 0; dp < 2; ++dp) {
            int dk = dp * 16 + fr;
            short8 ak = *(const short8*)(kT + (w >> 1) * 4096 + dk * 128 +
                                         ((ks * 64 + fq * 16) ^ ((dk & 7) << 4)));
            cacc[p][dp] = __builtin_amdgcn_mfma_f32_16x16x32_bf16(
                ak, bv, cacc[p][dp], 0, 0, 0);
          }
        }
      }
      __syncthreads();
    }
  }

  // ---- block epilogue: pctx + pksum ----
#pragma unroll
  for (int p = 0; p < 4; ++p) {
    const int head = 2 * p + (w >> 1);
    float* pc = pctx + ((size_t)(blk * 8 + head)) * 1024;
#pragma unroll
    for (int dp = 0; dp < 2; ++dp)
#pragma unroll
      for (int reg = 0; reg < 4; ++reg) {
        int dd = dp * 16 + fq * 4 + reg;
        int ee = (w & 1) * 16 + fr;
        pc[dd * 32 + ee] = cacc[p][dp][reg];
      }
    if (fq == 0)
      pksum[((size_t)(blk * 8 + head)) * 32 + (w & 1) * 16 + fr] = ksr[p];
  }
}

// ---------------------------------------------------------------------------
// ctx_final2: reduce 64 block-partials per (b,h) -> ctxT bf16 hi/lo + ksum
// ---------------------------------------------------------------------------
__global__ __launch_bounds__(256) void ctx_final2(
    const float* __restrict__ pctx, const float* __restrict__ pksum,
    unsigned short* __restrict__ ctxT, float* __restrict__ ksum) {
  int bh = blockIdx.x;  // 64
  int b = bh >> 3, h = bh & 7;
  int t = threadIdx.x;
  int d = t >> 3, e4 = (t & 7) * 4;
  float s[4] = {0.f, 0.f, 0.f, 0.f};
  for (int j = 0; j < 64; ++j) {
    const float* q =
        pctx + ((size_t)((b * 64 + j) * 8 + h)) * 1024 + d * 32 + e4;
    s[0] += q[0];
    s[1] += q[1];
    s[2] += q[2];
    s[3] += q[3];
  }
  unsigned short* cc = ctxT + (size_t)bh * 2048;
#pragma unroll
  for (int e2 = 0; e2 < 4; ++e2) {
    int e = e4 + e2;
    unsigned short hi = f2bf(s[e2]);
    float lo = s[e2] - bf2f(hi);
    cc[e * 32 + d] = hi;
    cc[1024 + e * 32 + d] = f2bf(lo);
  }
  __shared__ float ksp[8][32];
  int d2 = t & 31, ch = t >> 5;
  float ss = 0.f;
  for (int j = ch; j < 64; j += 8)
    ss += pksum[((size_t)((b * 64 + j) * 8 + h)) * 32 + d2];
  ksp[ch][d2] = ss;
  __syncthreads();
  if (t < 32) {
    float r = 0.f;
#pragma unroll
    for (int c = 0; c < 8; ++c) r += ksp[c][t];
    ksum[bh * 32 + t] = r;
  }
}

// ---------------------------------------------------------------------------
// FUSED attn + out-projection (round-7/8 proven, unchanged).
// ---------------------------------------------------------------------------
__global__ __launch_bounds__(512) void attn_proj(
    const unsigned short* __restrict__ Q,
    const unsigned short* __restrict__ ctxT,
    const float* __restrict__ ksum,
    const unsigned short* __restrict__ wpb,
    const float* __restrict__ bias,
    float* __restrict__ out) {
  const int t = threadIdx.x;
  const int lane = t & 63, w = t >> 6;  // 8 waves
  const int panel = blockIdx.x;         // 1024
  const int b = panel >> 7;
  const size_t row0 = (size_t)panel * 128;
  const int l5 = lane & 31;
  const int rpar = lane >> 5;
  const int fr = lane & 15, fq = lane >> 4;

  __shared__ __align__(16) unsigned char qa[65536];
  __shared__ __align__(16) unsigned char wpB[2][32768];
  __shared__ float ksumL[256];
  __shared__ float Dinv_s[128][8];

#pragma unroll
  for (int s = 0; s < 8; ++s) {
    int seg = w * 8 + s;
    int row = seg * 2 + rpar;
    gload16((const char*)Q + (row0 + row) * 512 + ((l5 * 16) ^ ((row & 7) << 4)),
            qa + seg * 1024);
  }
#pragma unroll
  for (int s = 0; s < 4; ++s) {
    int seg = w * 4 + s;
    gload16((const char*)ctxT + (size_t)b * 32768 + seg * 1024 + lane * 16,
            wpB[1] + seg * 1024);
  }
  if (w == 0) gload16((const char*)(ksum + b * 256) + lane * 16, (void*)ksumL);
  __syncthreads();

#pragma unroll
  for (int ii = 0; ii < 2; ++ii) {
    int pp = t + ii * 512;
    int r = pp >> 3, h = pp & 7;
    const unsigned char* qrow = qa + r * 512;
    int swzr = (r & 7) << 4;
    float s = 0.f;
#pragma unroll
    for (int dd = 0; dd < 16; ++dd) {
      unsigned u = *(const unsigned*)(qrow + ((h * 64 + dd * 4) ^ swzr));
      s += __uint_as_float(u << 16) * ksumL[h * 32 + dd * 2] +
           __uint_as_float(u & 0xffff0000u) * ksumL[h * 32 + dd * 2 + 1];
    }
    Dinv_s[r][h] = 1.f / fmaxf(s, 1e-6f);
  }

  const int wrow = w >> 2, cw = w & 3;
  f32x4 sacc[2][4][2];
#pragma unroll
  for (int h2 = 0; h2 < 2; ++h2)
#pragma unroll
    for (int i = 0; i < 4; ++i)
#pragma unroll
      for (int j = 0; j < 2; ++j)
#pragma unroll
        for (int c = 0; c < 4; ++c) sacc[h2][i][j][c] = 0.f;

#pragma unroll
  for (int h2 = 0; h2 < 2; ++h2) {
    int h = 2 * cw + h2;
#pragma unroll
    for (int i = 0; i < 4; ++i) {
      int ra = wrow * 64 + i * 16 + fr;
      short8 af = *(const short8*)(qa + ra * 512 +
                                   ((h * 64 + fq * 16) ^ ((ra & 7) << 4)));
#pragma unroll
      for (int j = 0; j < 2; ++j) {
        int rb = j * 16 + fr;
        short8 bhi = *(const short8*)(wpB[1] + h * 4096 + rb * 64 + fq * 16);
        short8 blo = *(const short8*)(wpB[1] + h * 4096 + 2048 + rb * 64 + fq * 16);
        sacc[h2][i][j] = __builtin_amdgcn_mfma_f32_16x16x32_bf16(
            af, bhi, sacc[h2][i][j], 0, 0, 0);
        sacc[h2][i][j] = __builtin_amdgcn_mfma_f32_16x16x32_bf16(
            af, blo, sacc[h2][i][j], 0, 0, 0);
      }
    }
  }
  __syncthreads();

#pragma unroll
  for (int h2 = 0; h2 < 2; ++h2) {
    int h = 2 * cw + h2;
#pragma unroll
    for (int i = 0; i < 4; ++i)
#pragma unroll
      for (int j = 0; j < 2; ++j)
#pragma unroll
        for (int reg = 0; reg < 4; ++reg) {
          int r = wrow * 64 + i * 16 + fq * 4 + reg;
          int c = h * 32 + j * 16 + fr;
          float v = sacc[h2][i][j][reg] * Dinv_s[r][h];
          *(unsigned short*)(qa + r * 512 + ((2 * c) ^ ((r & 7) << 4))) = f2bf(v);
        }
  }

  for (int q = 0; q < 4; ++q) {
    unsigned char* wbuf = wpB[q & 1];
    unsigned char* scr = wpB[(q & 1) ^ 1];
#pragma unroll
    for (int s = 0; s < 4; ++s) {
      int seg = w * 4 + s;
      int rowl = seg * 2 + rpar;
      gload16((const char*)wpb + (size_t)(q * 64 + rowl) * 512 +
                  ((l5 * 16) ^ ((rowl & 7) << 4)),
              wbuf + seg * 1024);
    }
    __syncthreads();

    f32x4 oacc[4];
#pragma unroll
    for (int j = 0; j < 4; ++j)
#pragma unroll
      for (int c = 0; c < 4; ++c) oacc[j][c] = 0.f;
    const int ra = w * 16 + fr;
    const int sra = (ra & 7) << 4;
#pragma unroll
    for (int kk = 0; kk < 8; ++kk) {
      short8 af = *(const short8*)(qa + ra * 512 + ((kk * 64 + fq * 16) ^ sra));
#pragma unroll
      for (int j = 0; j < 4; ++j) {
        int rb = j * 16 + fr;
        short8 bf8 = *(const short8*)(wbuf + rb * 512 +
                                      ((kk * 64 + fq * 16) ^ ((rb & 7) << 4)));
        oacc[j] = __builtin_amdgcn_mfma_f32_16x16x32_bf16(af, bf8, oacc[j], 0, 0, 0);
      }
    }
    unsigned char* ws4 = scr + w * 4096;
#pragma unroll
    for (int j = 0; j < 4; ++j) {
      float bj = bias[q * 64 + j * 16 + fr];
#pragma unroll
      for (int reg = 0; reg < 4; ++reg) {
        int ri = fq * 4 + reg;
        int cb = (j * 16 + fr) * 4;
        *(float*)(ws4 + ri * 256 + (cb ^ ((ri & 7) << 4))) = oacc[j][reg] + bj;
      }
    }
#pragma unroll
    for (int c = 0; c < 4; ++c) {
      int ri = lane >> 2;
      int cb = (lane & 3) * 16 + c * 64;
      uint4 u = *(const uint4*)(ws4 + ri * 256 + (cb ^ ((ri & 7) << 4)));
      *(uint4*)((char*)(out + (row0 + w * 16 + ri) * 256 + q * 64) + cb) = u;
    }
    __syncthreads();
  }
}

// ---------------------------------------------------------------------------
extern "C" void kernel_launch(void* const* d_in, const int* in_sizes, int n_in,
                              void* d_out, int out_size, void* d_ws, size_t ws_size,
                              hipStream_t stream) {
  const float* x = (const float*)d_in[0];
  const float* Wq = (const float*)d_in[1];
  const float* Wkv = (const float*)d_in[2];
  const float* Wproj = (const float*)d_in[3];
  const float* bproj = (const float*)d_in[4];
  float* out = (float*)d_out;

  char* ws = (char*)d_ws;
  unsigned short* Q = (unsigned short*)(ws);                 // 67,108,864
  unsigned short* wcat = (unsigned short*)(ws + 67108864);   // 393,216
  unsigned short* wpb = (unsigned short*)(ws + 67502080);    // 131,072
  float* pctx = (float*)(ws + 67633152);                     // 16,777,216
  float* pksum = (float*)(ws + 84410368);                    // 524,288
  unsigned short* ctxT = (unsigned short*)(ws + 84934656);   // 262,144
  float* ksum = (float*)(ws + 85196800);                     // 8,192

  prep_w<<<1024, 256, 0, stream>>>(Wq, Wkv, Wproj, wcat, wpb);
  qkv_ctx<<<512, 256, 0, stream>>>(x, wcat, Q, pctx, pksum);
  ctx_final2<<<64, 256, 0, stream>>>(pctx, pksum, ctxT, ksum);
  attn_proj<<<1024, 512, 0, stream>>>(Q, ctxT, ksum, wpb, bproj, out);
}

// Round 10
// 276.789 us; speedup vs baseline: 1.9287x; 1.9287x over previous
//
#include <hip/hip_runtime.h>
#include <hip/hip_bf16.h>
#include <cstdint>
#include <cstddef>

typedef __attribute__((ext_vector_type(8))) short short8;
typedef __attribute__((ext_vector_type(4))) float f32x4;

#define DEVI static __device__ __forceinline__

DEVI unsigned short f2bf(float f) {
  unsigned u = __float_as_uint(f);
  unsigned r = u + 0x7fffu + ((u >> 16) & 1u);
  return (unsigned short)(r >> 16);
}
DEVI float bf2f(unsigned short s) {
  return __uint_as_float(((unsigned)s) << 16);
}
DEVI unsigned pack2(float a, float b) {
  return (unsigned)f2bf(a) | ((unsigned)f2bf(b) << 16);
}

DEVI void gload16(const void* g, void* l) {
  __builtin_amdgcn_global_load_lds(
      (__attribute__((address_space(1))) void*)g,
      (__attribute__((address_space(3))) void*)l, 16, 0, 0);
}

// ---------------------------------------------------------------------------
// prep_w: Wq/Wkv -> wcat bf16 [768][256] (plain layout), Wproj -> wpb
// ---------------------------------------------------------------------------
__global__ __launch_bounds__(256) void prep_w(
    const float* __restrict__ Wq, const float* __restrict__ Wkv,
    const float* __restrict__ Wp, unsigned short* __restrict__ wcat,
    unsigned short* __restrict__ wpb) {
  int i = blockIdx.x * 256 + threadIdx.x;  // grid 1024
  if (i < 196608) {
    float v = (i < 65536) ? Wq[i] : Wkv[i - 65536];
    wcat[i] = f2bf(v);
  } else {
    int j = i - 196608;
    wpb[j] = f2bf(Wp[j]);
  }
}

// ---------------------------------------------------------------------------
// qkv_ctx (round-8 structure + surgical fixes):
// 512 blocks x 256 thr (4 waves), 4 panels of 64 rows each.
// Per panel: x->bf16 LDS (slot-bijection, conflict-free); 24 slivers of 32
// W-rows each, ping-pong gload_lds:
//   s0..7  Q (operand-SWAPPED mfma -> lane holds 4 consecutive Q cols; b64
//          bounce in wave-private 1KB; 64B-coalesced global stores)
//   s8+2h  K head h (elu -> kT[32d][64n] transposed; ksum via shfl)
//   s9+2h  V head h (-> vT); ctx MFMA accumulates into cacc[h] registers
// Block epilogue: pctx[blk][8][32][32] + pksum[blk][4][8][32].
// LDS 72KB (xa 32K, wb0/wb1 16K, kT/vT 4K) -> 2 blocks/CU.
// ---------------------------------------------------------------------------
__global__ __launch_bounds__(256, 2) void qkv_ctx(
    const float* __restrict__ x, const unsigned short* __restrict__ wcat,
    unsigned short* __restrict__ Q, float* __restrict__ pctx,
    float* __restrict__ pksum) {
  const int t = threadIdx.x;
  const int lane = t & 63, w = t >> 6;
  const int fr = lane & 15, fq = lane >> 4;
  const int blk = blockIdx.x;  // 512

  __shared__ __align__(16) unsigned char smem[73728];
  unsigned char* const xa = smem;            // 32KB [64][512B]
  unsigned char* const wb0 = smem + 32768;   // 16KB [32][512B]
  unsigned char* const wb1 = smem + 49152;   // 16KB
  unsigned char* const kT = smem + 65536;    // 4KB [32 d][128B] (+Q bounce)
  unsigned char* const vT = smem + 69632;    // 4KB

  f32x4 cacc[8];
  float ksr[8][2];
#pragma unroll
  for (int h = 0; h < 8; ++h) {
#pragma unroll
    for (int c = 0; c < 4; ++c) cacc[h][c] = 0.f;
    ksr[h][0] = 0.f;
    ksr[h][1] = 0.f;
  }

  const int segr = lane >> 5;
  const int segc = (lane & 31) * 16;
  auto stage_w = [&](unsigned char* buf, int sl) {
    int wr0 = (sl < 8) ? sl * 32
                       : (((sl & 1) == 0) ? 256 + ((sl - 8) >> 1) * 32
                                          : 512 + ((sl - 8) >> 1) * 32);
#pragma unroll
    for (int i = 0; i < 4; ++i) {
      int seg = w * 4 + i;
      int rloc = seg * 2 + segr;
      gload16((const char*)wcat + (size_t)(wr0 + rloc) * 512 +
                  (segc ^ ((rloc & 7) << 4)),
              buf + seg * 1024);
    }
  };

  auto ctx_head = [&](int h) {  // h must be compile-time at each call site
    const int dp = w >> 1, ep = w & 1;
    const int rka = dp * 16 + fr;
    const int rkb = ep * 16 + fr;
#pragma unroll
    for (int ks = 0; ks < 2; ++ks) {
      short8 ak = *(const short8*)(kT + rka * 128 +
                                   ((ks * 64 + fq * 16) ^ ((rka & 7) << 4)));
      short8 bv = *(const short8*)(vT + rkb * 128 +
                                   ((ks * 64 + fq * 16) ^ ((rkb & 7) << 4)));
      cacc[h] = __builtin_amdgcn_mfma_f32_16x16x32_bf16(ak, bv, cacc[h], 0, 0, 0);
    }
  };

  const int xrow_l = w * 16 + fr;          // this wave's x-row for frags
  const int sxa = (xrow_l & 7) << 4;
  unsigned char* const bb = kT + w * 1024; // wave-private Q bounce [16][64B]

  stage_w(wb0, 0);

  for (int pp = 0; pp < 4; ++pp) {
    const size_t prow0 = (size_t)blk * 256 + (size_t)pp * 64;

    // ---- stage x panel (bf16, slot bijection: conflict-free) ----
    {
      const int r = t >> 2, qt = t & 3;
      const float* xrow = x + (prow0 + r) * 256;
      unsigned char* drow = xa + r * 512;
      const int swz = (r & 7) << 4;
#pragma unroll
      for (int i = 0; i < 8; ++i) {
        float4 a = *(const float4*)(xrow + i * 32 + qt * 8);
        float4 b2 = *(const float4*)(xrow + i * 32 + qt * 8 + 4);
        uint4 u;
        u.x = pack2(a.x, a.y);
        u.y = pack2(a.z, a.w);
        u.z = pack2(b2.x, b2.y);
        u.w = pack2(b2.z, b2.w);
        int slot = (i >> 1) * 8 + qt * 2 + (i & 1);  // sigma(i*4+qt)
        *(uint4*)(drow + ((slot * 16) ^ swz)) = u;
      }
    }
    __syncthreads();  // xa + wb0(s=0) ready

    // ================= Q phase: slivers 0..7 (swapped operands) ============
#pragma unroll
    for (int s = 0; s < 8; ++s) {
      stage_w((s & 1) ? wb0 : wb1, s + 1);
      const unsigned char* wbuf = (s & 1) ? wb1 : wb0;
      f32x4 qacc[2] = {{0.f, 0.f, 0.f, 0.f}, {0.f, 0.f, 0.f, 0.f}};
#pragma unroll
      for (int ks = 0; ks < 8; ++ks) {
        int slot = (ks >> 1) * 8 + fq * 2 + (ks & 1);
        short8 xf = *(const short8*)(xa + xrow_l * 512 + ((slot * 16) ^ sxa));
#pragma unroll
        for (int jW = 0; jW < 2; ++jW) {
          int rb = jW * 16 + fr;
          short8 wf = *(const short8*)(wbuf + rb * 512 +
                                       ((ks * 64 + fq * 16) ^ ((rb & 7) << 4)));
          qacc[jW] = __builtin_amdgcn_mfma_f32_16x16x32_bf16(wf, xf, qacc[jW],
                                                             0, 0, 0);
        }
      }
      // lane holds Q[x-row w*16+fr][cols s*32 + jW*16 + fq*4 + 0..3]
#pragma unroll
      for (int jW = 0; jW < 2; ++jW) {
        float v0 = qacc[jW][0], v1 = qacc[jW][1];
        float v2 = qacc[jW][2], v3 = qacc[jW][3];
        v0 = (v0 > 0.f) ? (v0 + 1.f) : __expf(v0);
        v1 = (v1 > 0.f) ? (v1 + 1.f) : __expf(v1);
        v2 = (v2 > 0.f) ? (v2 + 1.f) : __expf(v2);
        v3 = (v3 > 0.f) ? (v3 + 1.f) : __expf(v3);
        uint2 pk;
        pk.x = pack2(v0, v1);
        pk.y = pack2(v2, v3);
        *(uint2*)(bb + fr * 64 + ((jW * 32 + fq * 8) ^ ((fr & 3) << 4))) = pk;
      }
      {
        int rq = lane >> 2, c4 = lane & 3;
        uint4 u = *(const uint4*)(bb + rq * 64 + ((c4 * 16) ^ ((rq & 3) << 4)));
        *(uint4*)((char*)Q + (prow0 + w * 16 + rq) * 512 + s * 64 + c4 * 16) = u;
      }
      __syncthreads();
    }

    // ================= K/V phase: heads 0..7 (K in wb0, V in wb1) ==========
#pragma unroll
    for (int h = 0; h < 8; ++h) {
      const int sk = 8 + 2 * h;
      stage_w(wb1, sk + 1);  // V head h
      f32x4 acc[2] = {{0.f, 0.f, 0.f, 0.f}, {0.f, 0.f, 0.f, 0.f}};
#pragma unroll
      for (int ks = 0; ks < 8; ++ks) {
        int slot = (ks >> 1) * 8 + fq * 2 + (ks & 1);
        short8 xf = *(const short8*)(xa + xrow_l * 512 + ((slot * 16) ^ sxa));
#pragma unroll
        for (int j = 0; j < 2; ++j) {
          int rb = j * 16 + fr;
          short8 wf = *(const short8*)(wb0 + rb * 512 +
                                       ((ks * 64 + fq * 16) ^ ((rb & 7) << 4)));
          acc[j] = __builtin_amdgcn_mfma_f32_16x16x32_bf16(xf, wf, acc[j],
                                                           0, 0, 0);
        }
      }
      if (h > 0) ctx_head(h - 1);  // reads kT/vT of h-1 (compile-time index)
      __syncthreads();             // ctx reads done; V staged; K reads done

      // write kT (elu) + ksum partials
#pragma unroll
      for (int j = 0; j < 2; ++j) {
        float ps = 0.f;
#pragma unroll
        for (int reg = 0; reg < 4; ++reg) {
          int n = w * 16 + fq * 4 + reg;
          int d = j * 16 + fr;
          float v = acc[j][reg];
          v = (v > 0.f) ? (v + 1.f) : __expf(v);
          ps += v;
          *(unsigned short*)(kT + d * 128 + ((n * 2) ^ ((d & 7) << 4))) = f2bf(v);
        }
        ps += __shfl_xor(ps, 16, 64);
        ps += __shfl_xor(ps, 32, 64);
        ksr[h][j] += ps;
      }

      stage_w(wb0, (sk + 2 < 24) ? (sk + 2) : 0);  // K head h+1 (or wrap)
      f32x4 vacc[2] = {{0.f, 0.f, 0.f, 0.f}, {0.f, 0.f, 0.f, 0.f}};
#pragma unroll
      for (int ks = 0; ks < 8; ++ks) {
        int slot = (ks >> 1) * 8 + fq * 2 + (ks & 1);
        short8 xf = *(const short8*)(xa + xrow_l * 512 + ((slot * 16) ^ sxa));
#pragma unroll
        for (int j = 0; j < 2; ++j) {
          int rb = j * 16 + fr;
          short8 wf = *(const short8*)(wb1 + rb * 512 +
                                       ((ks * 64 + fq * 16) ^ ((rb & 7) << 4)));
          vacc[j] = __builtin_amdgcn_mfma_f32_16x16x32_bf16(xf, wf, vacc[j],
                                                            0, 0, 0);
        }
      }
      __syncthreads();  // kT write visible; V reads done; K(h+1) staged

#pragma unroll
      for (int j = 0; j < 2; ++j)
#pragma unroll
        for (int reg = 0; reg < 4; ++reg) {
          int n = w * 16 + fq * 4 + reg;
          int e = j * 16 + fr;
          *(unsigned short*)(vT + e * 128 + ((n * 2) ^ ((e & 7) << 4))) =
              f2bf(vacc[j][reg]);
        }
      __syncthreads();  // vT visible for ctx_head(h)
    }
    ctx_head(7);
  }

  // ---- block epilogue: pctx + pksum ----
  const int dp = w >> 1, ep = w & 1;
#pragma unroll
  for (int h = 0; h < 8; ++h) {
    float* pc = pctx + ((size_t)(blk * 8 + h)) * 1024;
#pragma unroll
    for (int reg = 0; reg < 4; ++reg) {
      int dd = dp * 16 + fq * 4 + reg;
      int ee = ep * 16 + fr;
      pc[dd * 32 + ee] = cacc[h][reg];
    }
    if (fq == 0) {
      size_t base = (((size_t)blk * 4 + w) * 8 + h) * 32;
      pksum[base + fr] = ksr[h][0];
      pksum[base + 16 + fr] = ksr[h][1];
    }
  }
}

// ---------------------------------------------------------------------------
// ctx_final2: reduce 64 block-partials (x4 wave ksum) per (b,h)
// ---------------------------------------------------------------------------
__global__ __launch_bounds__(256) void ctx_final2(
    const float* __restrict__ pctx, const float* __restrict__ pksum,
    unsigned short* __restrict__ ctxT, float* __restrict__ ksum) {
  int bh = blockIdx.x;  // 64
  int b = bh >> 3, h = bh & 7;
  int t = threadIdx.x;
  int d = t >> 3, e4 = (t & 7) * 4;
  float s[4] = {0.f, 0.f, 0.f, 0.f};
  for (int j = 0; j < 64; ++j) {
    const float* q = pctx + ((size_t)((b * 64 + j) * 8 + h)) * 1024 + d * 32 + e4;
    s[0] += q[0];
    s[1] += q[1];
    s[2] += q[2];
    s[3] += q[3];
  }
  unsigned short* cc = ctxT + (size_t)bh * 2048;
#pragma unroll
  for (int e2 = 0; e2 < 4; ++e2) {
    int e = e4 + e2;
    unsigned short hi = f2bf(s[e2]);
    float lo = s[e2] - bf2f(hi);
    cc[e * 32 + d] = hi;
    cc[1024 + e * 32 + d] = f2bf(lo);
  }
  __shared__ float ksp[8][32];
  int d2 = t & 31, ch = t >> 5;
  float ss = 0.f;
  for (int u = ch; u < 256; u += 8)  // u = (block-in-batch)*4 + wave
    ss += pksum[((size_t)(b * 256 + u) * 8 + h) * 32 + d2];
  ksp[ch][d2] = ss;
  __syncthreads();
  if (t < 32) {
    float r = 0.f;
#pragma unroll
    for (int c = 0; c < 8; ++c) r += ksp[c][t];
    ksum[bh * 32 + t] = r;
  }
}

// ---------------------------------------------------------------------------
// FUSED attn + out-projection (round-7/8 proven, unchanged).
// ---------------------------------------------------------------------------
__global__ __launch_bounds__(512) void attn_proj(
    const unsigned short* __restrict__ Q,
    const unsigned short* __restrict__ ctxT,
    const float* __restrict__ ksum,
    const unsigned short* __restrict__ wpb,
    const float* __restrict__ bias,
    float* __restrict__ out) {
  const int t = threadIdx.x;
  const int lane = t & 63, w = t >> 6;  // 8 waves
  const int panel = blockIdx.x;         // 1024
  const int b = panel >> 7;
  const size_t row0 = (size_t)panel * 128;
  const int l5 = lane & 31;
  const int rpar = lane >> 5;
  const int fr = lane & 15, fq = lane >> 4;

  __shared__ __align__(16) unsigned char qa[65536];
  __shared__ __align__(16) unsigned char wpB[2][32768];
  __shared__ float ksumL[256];
  __shared__ float Dinv_s[128][8];

#pragma unroll
  for (int s = 0; s < 8; ++s) {
    int seg = w * 8 + s;
    int row = seg * 2 + rpar;
    gload16((const char*)Q + (row0 + row) * 512 + ((l5 * 16) ^ ((row & 7) << 4)),
            qa + seg * 1024);
  }
#pragma unroll
  for (int s = 0; s < 4; ++s) {
    int seg = w * 4 + s;
    gload16((const char*)ctxT + (size_t)b * 32768 + seg * 1024 + lane * 16,
            wpB[1] + seg * 1024);
  }
  if (w == 0) gload16((const char*)(ksum + b * 256) + lane * 16, (void*)ksumL);
  __syncthreads();

#pragma unroll
  for (int ii = 0; ii < 2; ++ii) {
    int pp = t + ii * 512;
    int r = pp >> 3, h = pp & 7;
    const unsigned char* qrow = qa + r * 512;
    int swzr = (r & 7) << 4;
    float s = 0.f;
#pragma unroll
    for (int dd = 0; dd < 16; ++dd) {
      unsigned u = *(const unsigned*)(qrow + ((h * 64 + dd * 4) ^ swzr));
      s += __uint_as_float(u << 16) * ksumL[h * 32 + dd * 2] +
           __uint_as_float(u & 0xffff0000u) * ksumL[h * 32 + dd * 2 + 1];
    }
    Dinv_s[r][h] = 1.f / fmaxf(s, 1e-6f);
  }

  const int wrow = w >> 2, cw = w & 3;
  f32x4 sacc[2][4][2];
#pragma unroll
  for (int h2 = 0; h2 < 2; ++h2)
#pragma unroll
    for (int i = 0; i < 4; ++i)
#pragma unroll
      for (int j = 0; j < 2; ++j)
#pragma unroll
        for (int c = 0; c < 4; ++c) sacc[h2][i][j][c] = 0.f;

#pragma unroll
  for (int h2 = 0; h2 < 2; ++h2) {
    int h = 2 * cw + h2;
#pragma unroll
    for (int i = 0; i < 4; ++i) {
      int ra = wrow * 64 + i * 16 + fr;
      short8 af = *(const short8*)(qa + ra * 512 +
                                   ((h * 64 + fq * 16) ^ ((ra & 7) << 4)));
#pragma unroll
      for (int j = 0; j < 2; ++j) {
        int rb = j * 16 + fr;
        short8 bhi = *(const short8*)(wpB[1] + h * 4096 + rb * 64 + fq * 16);
        short8 blo = *(const short8*)(wpB[1] + h * 4096 + 2048 + rb * 64 + fq * 16);
        sacc[h2][i][j] = __builtin_amdgcn_mfma_f32_16x16x32_bf16(
            af, bhi, sacc[h2][i][j], 0, 0, 0);
        sacc[h2][i][j] = __builtin_amdgcn_mfma_f32_16x16x32_bf16(
            af, blo, sacc[h2][i][j], 0, 0, 0);
      }
    }
  }
  __syncthreads();

#pragma unroll
  for (int h2 = 0; h2 < 2; ++h2) {
    int h = 2 * cw + h2;
#pragma unroll
    for (int i = 0; i < 4; ++i)
#pragma unroll
      for (int j = 0; j < 2; ++j)
#pragma unroll
        for (int reg = 0; reg < 4; ++reg) {
          int r = wrow * 64 + i * 16 + fq * 4 + reg;
          int c = h * 32 + j * 16 + fr;
          float v = sacc[h2][i][j][reg] * Dinv_s[r][h];
          *(unsigned short*)(qa + r * 512 + ((2 * c) ^ ((r & 7) << 4))) = f2bf(v);
        }
  }

  for (int q = 0; q < 4; ++q) {
    unsigned char* wbuf = wpB[q & 1];
    unsigned char* scr = wpB[(q & 1) ^ 1];
#pragma unroll
    for (int s = 0; s < 4; ++s) {
      int seg = w * 4 + s;
      int rowl = seg * 2 + rpar;
      gload16((const char*)wpb + (size_t)(q * 64 + rowl) * 512 +
                  ((l5 * 16) ^ ((rowl & 7) << 4)),
              wbuf + seg * 1024);
    }
    __syncthreads();

    f32x4 oacc[4];
#pragma unroll
    for (int j = 0; j < 4; ++j)
#pragma unroll
      for (int c = 0; c < 4; ++c) oacc[j][c] = 0.f;
    const int ra = w * 16 + fr;
    const int sra = (ra & 7) << 4;
#pragma unroll
    for (int kk = 0; kk < 8; ++kk) {
      short8 af = *(const short8*)(qa + ra * 512 + ((kk * 64 + fq * 16) ^ sra));
#pragma unroll
      for (int j = 0; j < 4; ++j) {
        int rb = j * 16 + fr;
        short8 bf8 = *(const short8*)(wbuf + rb * 512 +
                                      ((kk * 64 + fq * 16) ^ ((rb & 7) << 4)));
        oacc[j] = __builtin_amdgcn_mfma_f32_16x16x32_bf16(af, bf8, oacc[j], 0, 0, 0);
      }
    }
    unsigned char* ws4 = scr + w * 4096;
#pragma unroll
    for (int j = 0; j < 4; ++j) {
      float bj = bias[q * 64 + j * 16 + fr];
#pragma unroll
      for (int reg = 0; reg < 4; ++reg) {
        int ri = fq * 4 + reg;
        int cb = (j * 16 + fr) * 4;
        *(float*)(ws4 + ri * 256 + (cb ^ ((ri & 7) << 4))) = oacc[j][reg] + bj;
      }
    }
#pragma unroll
    for (int c = 0; c < 4; ++c) {
      int ri = lane >> 2;
      int cb = (lane & 3) * 16 + c * 64;
      uint4 u = *(const uint4*)(ws4 + ri * 256 + (cb ^ ((ri & 7) << 4)));
      *(uint4*)((char*)(out + (row0 + w * 16 + ri) * 256 + q * 64) + cb) = u;
    }
    __syncthreads();
  }
}

// ---------------------------------------------------------------------------
extern "C" void kernel_launch(void* const* d_in, const int* in_sizes, int n_in,
                              void* d_out, int out_size, void* d_ws, size_t ws_size,
                              hipStream_t stream) {
  const float* x = (const float*)d_in[0];
  const float* Wq = (const float*)d_in[1];
  const float* Wkv = (const float*)d_in[2];
  const float* Wproj = (const float*)d_in[3];
  const float* bproj = (const float*)d_in[4];
  float* out = (float*)d_out;

  char* ws = (char*)d_ws;
  unsigned short* Q = (unsigned short*)(ws);                // 67,108,864
  unsigned short* wcat = (unsigned short*)(ws + 67108864);  // 393,216
  unsigned short* wpb = (unsigned short*)(ws + 67502080);   // 131,072
  float* pctx = (float*)(ws + 67633152);                    // 16,777,216
  float* pksum = (float*)(ws + 84410368);                   // 2,097,152
  unsigned short* ctxT = (unsigned short*)(ws + 86507520);  // 262,144
  float* ksum = (float*)(ws + 86769664);                    // 8,192

  prep_w<<<1024, 256, 0, stream>>>(Wq, Wkv, Wproj, wcat, wpb);
  qkv_ctx<<<512, 256, 0, stream>>>(x, wcat, Q, pctx, pksum);
  ctx_final2<<<64, 256, 0, stream>>>(pctx, pksum, ctxT, ksum);
  attn_proj<<<1024, 512, 0, stream>>>(Q, ctxT, ksum, wpb, bproj, out);
}

// Round 11
// 249.938 us; speedup vs baseline: 2.1358x; 1.1074x over previous
//
#include <hip/hip_runtime.h>
#include <hip/hip_bf16.h>
#include <cstdint>
#include <cstddef>

typedef __attribute__((ext_vector_type(8))) short short8;
typedef __attribute__((ext_vector_type(4))) float f32x4;

#define DEVI static __device__ __forceinline__

DEVI unsigned short f2bf(float f) {
  unsigned u = __float_as_uint(f);
  unsigned r = u + 0x7fffu + ((u >> 16) & 1u);
  return (unsigned short)(r >> 16);
}
DEVI float bf2f(unsigned short s) {
  return __uint_as_float(((unsigned)s) << 16);
}
DEVI unsigned pack2(float a, float b) {
  return (unsigned)f2bf(a) | ((unsigned)f2bf(b) << 16);
}

DEVI void gload16(const void* g, void* l) {
  __builtin_amdgcn_global_load_lds(
      (__attribute__((address_space(1))) void*)g,
      (__attribute__((address_space(3))) void*)l, 16, 0, 0);
}

// ---------------------------------------------------------------------------
// prep_w: Wq/Wkv -> wcat bf16 [768][256], Wproj -> wpb bf16 [256][256]
// ---------------------------------------------------------------------------
__global__ __launch_bounds__(256) void prep_w(
    const float* __restrict__ Wq, const float* __restrict__ Wkv,
    const float* __restrict__ Wp, unsigned short* __restrict__ wcat,
    unsigned short* __restrict__ wpb) {
  int i = blockIdx.x * 256 + threadIdx.x;
  if (i < 196608) {
    float v = (i < 65536) ? Wq[i] : Wkv[i - 65536];
    wcat[i] = f2bf(v);
  } else {
    int j = i - 196608;
    wpb[j] = f2bf(Wp[j]);
  }
}

// ---------------------------------------------------------------------------
// MEGA qkv_ctx (round-8 structure, conflict-fixed):
// 2048 blocks x 256 thr (4 waves), one 64-row panel each. 24 W-slivers
// (32 rows), ping-pong gload_lds:
//  s0..7   Q slivers: SWAPPED mfma(wf,xf) -> lane holds 4 consecutive Q-cols;
//          wave-private 80B-stride bounce, b64 writes, b128 read, 64B stores.
//  s8+2h   K head h: elu -> kT[32d][64n] transposed, PACKED b64 writes.
//  s9+2h   V head h: -> vT packed; ctx+ksum MFMA per head (ones-operand).
// pctx[panel][h][32d][32e] fp32 + pksum[panel][h][32d].
// LDS 72KB: xa 32K (slot-bijection layout), wb0/wb1 16K, kT/vT 4K.
// ---------------------------------------------------------------------------
__global__ __launch_bounds__(256) void qkv_ctx(
    const float* __restrict__ x, const unsigned short* __restrict__ wcat,
    unsigned short* __restrict__ Q, float* __restrict__ pctx,
    float* __restrict__ pksum) {
  const int t = threadIdx.x;
  const int lane = t & 63, w = t >> 6;  // 4 waves
  const int p = blockIdx.x;             // 2048 panels of 64 rows
  const size_t row0 = (size_t)p * 64;
  const int fr = lane & 15, fq = lane >> 4;

  __shared__ __align__(16) unsigned char smem[73728];
  unsigned char* const xa = smem;            // 32KB [64][512B] sigma-slots ^((r&7)<<4)
  unsigned char* const wb0 = smem + 32768;   // 16KB [32][512B]
  unsigned char* const wb1 = smem + 49152;   // 16KB
  unsigned char* const kT = smem + 65536;    // 4KB [32 d][128B] ^((d&7)<<4)
  unsigned char* const vT = smem + 69632;    // 4KB

  const short ob = (short)0x3F80;
  const short8 ones = {ob, ob, ob, ob, ob, ob, ob, ob};

  // ---- stage xa: fp32 -> bf16, slot bijection (conflict-free) ----
  {
    const int r = t >> 2, qt = t & 3;
    const float* xrow = x + (row0 + r) * 256;
    unsigned char* drow = xa + r * 512;
    const int swz = (r & 7) << 4;
#pragma unroll
    for (int i = 0; i < 8; ++i) {
      float4 a = *(const float4*)(xrow + i * 32 + qt * 8);
      float4 b2 = *(const float4*)(xrow + i * 32 + qt * 8 + 4);
      uint4 u;
      u.x = pack2(a.x, a.y);
      u.y = pack2(a.z, a.w);
      u.z = pack2(b2.x, b2.y);
      u.w = pack2(b2.z, b2.w);
      int slot = (i >> 1) * 8 + qt * 2 + (i & 1);  // sigma(i*4+qt)
      *(uint4*)(drow + ((slot * 16) ^ swz)) = u;
    }
  }

  const int segr = lane >> 5;
  const int segc = (lane & 31) * 16;
  auto stage_w = [&](unsigned char* buf, int s) {
    int wr0 = (s < 8) ? s * 32
                      : (((s & 1) == 0) ? 256 + ((s - 8) >> 1) * 32
                                        : 512 + ((s - 8) >> 1) * 32);
#pragma unroll
    for (int i = 0; i < 4; ++i) {
      int seg = w * 4 + i;
      int rloc = seg * 2 + segr;
      gload16((const char*)wcat + (size_t)(wr0 + rloc) * 512 +
                  (segc ^ ((rloc & 7) << 4)),
              buf + seg * 1024);
    }
  };

  auto ctx_head = [&](int h) {
    const int dp = w >> 1, ep = w & 1;
    f32x4 cacc = {0.f, 0.f, 0.f, 0.f};
    f32x4 sacc = {0.f, 0.f, 0.f, 0.f};
    const int rka = dp * 16 + fr;
    const int rkb = ep * 16 + fr;
#pragma unroll
    for (int ks = 0; ks < 2; ++ks) {
      short8 ak = *(const short8*)(kT + rka * 128 +
                                   ((ks * 64 + fq * 16) ^ ((rka & 7) << 4)));
      short8 bv = *(const short8*)(vT + rkb * 128 +
                                   ((ks * 64 + fq * 16) ^ ((rkb & 7) << 4)));
      cacc = __builtin_amdgcn_mfma_f32_16x16x32_bf16(ak, bv, cacc, 0, 0, 0);
      if (ep == 0)
        sacc = __builtin_amdgcn_mfma_f32_16x16x32_bf16(ak, ones, sacc, 0, 0, 0);
    }
    float* pc = pctx + ((size_t)(p * 8 + h)) * 1024;
#pragma unroll
    for (int reg = 0; reg < 4; ++reg) {
      int d = dp * 16 + fq * 4 + reg;
      int e = ep * 16 + fr;
      pc[d * 32 + e] = cacc[reg];
    }
    if (ep == 0 && fr == 0) {
#pragma unroll
      for (int reg = 0; reg < 4; ++reg) {
        int d = dp * 16 + fq * 4 + reg;
        pksum[((size_t)(p * 8 + h)) * 32 + d] = sacc[reg];
      }
    }
  };

  stage_w(wb0, 0);
  __syncthreads();

  const int ra = w * 16 + fr;
  const int sra = (ra & 7) << 4;
  unsigned char* const bb = kT + w * 1280;  // wave-private bounce [16][80B]

  for (int s = 0; s < 24; ++s) {
    if (s >= 10 && (s & 1) == 0) ctx_head((s - 10) >> 1);
    if (s < 23) stage_w(((s & 1) == 0) ? wb1 : wb0, s + 1);

    const unsigned char* wbuf = ((s & 1) == 0) ? wb0 : wb1;

    if (s < 8) {
      // ---- Q sliver: swapped operands -> lane has 4 consecutive Q-cols ----
      f32x4 acc[2] = {{0.f, 0.f, 0.f, 0.f}, {0.f, 0.f, 0.f, 0.f}};
#pragma unroll
      for (int ks = 0; ks < 8; ++ks) {
        int slot = (ks >> 1) * 8 + fq * 2 + (ks & 1);
        short8 xf = *(const short8*)(xa + ra * 512 + ((slot * 16) ^ sra));
#pragma unroll
        for (int j = 0; j < 2; ++j) {
          int rb = j * 16 + fr;
          short8 wf = *(const short8*)(wbuf + rb * 512 +
                                       ((ks * 64 + fq * 16) ^ ((rb & 7) << 4)));
          acc[j] = __builtin_amdgcn_mfma_f32_16x16x32_bf16(wf, xf, acc[j],
                                                           0, 0, 0);
        }
      }
      // bounce: row = x-row (fr), 80B stride, b64 packed (elu applied)
#pragma unroll
      for (int j = 0; j < 2; ++j) {
        float v0 = acc[j][0], v1 = acc[j][1], v2 = acc[j][2], v3 = acc[j][3];
        v0 = (v0 > 0.f) ? (v0 + 1.f) : __expf(v0);
        v1 = (v1 > 0.f) ? (v1 + 1.f) : __expf(v1);
        v2 = (v2 > 0.f) ? (v2 + 1.f) : __expf(v2);
        v3 = (v3 > 0.f) ? (v3 + 1.f) : __expf(v3);
        uint2 pk;
        pk.x = pack2(v0, v1);
        pk.y = pack2(v2, v3);
        *(uint2*)(bb + fr * 80 + j * 32 + fq * 8) = pk;
      }
      // wave-local read (no barrier needed) -> 64B-coalesced store
      {
        int rowq = lane >> 2, c4 = lane & 3;
        uint4 u = *(const uint4*)(bb + rowq * 80 + c4 * 16);
        *(uint4*)((char*)Q + (row0 + w * 16 + rowq) * 512 + s * 64 + c4 * 16) = u;
      }
    } else {
      // ---- K/V sliver: normal orientation, packed b64 transposed writes ----
      f32x4 acc[2] = {{0.f, 0.f, 0.f, 0.f}, {0.f, 0.f, 0.f, 0.f}};
#pragma unroll
      for (int ks = 0; ks < 8; ++ks) {
        int slot = (ks >> 1) * 8 + fq * 2 + (ks & 1);
        short8 xf = *(const short8*)(xa + ra * 512 + ((slot * 16) ^ sra));
#pragma unroll
        for (int j = 0; j < 2; ++j) {
          int rb = j * 16 + fr;
          short8 wf = *(const short8*)(wbuf + rb * 512 +
                                       ((ks * 64 + fq * 16) ^ ((rb & 7) << 4)));
          acc[j] = __builtin_amdgcn_mfma_f32_16x16x32_bf16(xf, wf, acc[j],
                                                           0, 0, 0);
        }
      }
      __syncthreads();  // previous ctx_head reads done before kT/vT overwrite

      const bool isK = ((s & 1) == 0);
      unsigned char* dstT = isK ? kT : vT;
#pragma unroll
      for (int j = 0; j < 2; ++j) {
        int d = j * 16 + fr;
        float v0 = acc[j][0], v1 = acc[j][1], v2 = acc[j][2], v3 = acc[j][3];
        if (isK) {
          v0 = (v0 > 0.f) ? (v0 + 1.f) : __expf(v0);
          v1 = (v1 > 0.f) ? (v1 + 1.f) : __expf(v1);
          v2 = (v2 > 0.f) ? (v2 + 1.f) : __expf(v2);
          v3 = (v3 > 0.f) ? (v3 + 1.f) : __expf(v3);
        }
        uint2 pk;
        pk.x = pack2(v0, v1);
        pk.y = pack2(v2, v3);
        // 4 consecutive n = w*16+fq*4.. ; 16B-granular XOR keeps 8B alignment
        *(uint2*)(dstT + d * 128 + ((w * 32 + fq * 8) ^ ((d & 7) << 4))) = pk;
      }
    }
    __syncthreads();
  }
  ctx_head(7);
}

// ---------------------------------------------------------------------------
// ctx_final2: reduce 256 panel-partials per (b,h) -> ctxT bf16 hi/lo + ksum
// ---------------------------------------------------------------------------
__global__ __launch_bounds__(256) void ctx_final2(
    const float* __restrict__ pctx, const float* __restrict__ pksum,
    unsigned short* __restrict__ ctxT, float* __restrict__ ksum) {
  int bh = blockIdx.x;
  int b = bh >> 3, h = bh & 7;
  int t = threadIdx.x;
  int d = t >> 3, e4 = (t & 7) * 4;
  float s[4] = {0.f, 0.f, 0.f, 0.f};
  for (int pp = 0; pp < 256; ++pp) {
    const float* q = pctx + ((size_t)((b * 256 + pp) * 8 + h)) * 1024 + d * 32 + e4;
    s[0] += q[0]; s[1] += q[1]; s[2] += q[2]; s[3] += q[3];
  }
  unsigned short* cc = ctxT + (size_t)bh * 2048;
#pragma unroll
  for (int e2 = 0; e2 < 4; ++e2) {
    int e = e4 + e2;
    unsigned short hi = f2bf(s[e2]);
    float lo = s[e2] - bf2f(hi);
    cc[e * 32 + d] = hi;
    cc[1024 + e * 32 + d] = f2bf(lo);
  }
  __shared__ float ksp[8][32];
  int d2 = t & 31, ch = t >> 5;
  float ss = 0.f;
  for (int pp = ch; pp < 256; pp += 8)
    ss += pksum[((size_t)((b * 256 + pp) * 8 + h)) * 32 + d2];
  ksp[ch][d2] = ss;
  __syncthreads();
  if (t < 32) {
    float r = 0.f;
#pragma unroll
    for (int c = 0; c < 8; ++c) r += ksp[c][t];
    ksum[bh * 32 + t] = r;
  }
}

// ---------------------------------------------------------------------------
// FUSED attn + out-projection (round-7/8 proven, unchanged).
// ---------------------------------------------------------------------------
__global__ __launch_bounds__(512) void attn_proj(
    const unsigned short* __restrict__ Q,
    const unsigned short* __restrict__ ctxT,
    const float* __restrict__ ksum,
    const unsigned short* __restrict__ wpb,
    const float* __restrict__ bias,
    float* __restrict__ out) {
  const int t = threadIdx.x;
  const int lane = t & 63, w = t >> 6;  // 8 waves
  const int panel = blockIdx.x;         // 1024
  const int b = panel >> 7;
  const size_t row0 = (size_t)panel * 128;
  const int l5 = lane & 31;
  const int rpar = lane >> 5;
  const int fr = lane & 15, fq = lane >> 4;

  __shared__ __align__(16) unsigned char qa[65536];
  __shared__ __align__(16) unsigned char wpB[2][32768];
  __shared__ float ksumL[256];
  __shared__ float Dinv_s[128][8];

#pragma unroll
  for (int s = 0; s < 8; ++s) {
    int seg = w * 8 + s;
    int row = seg * 2 + rpar;
    gload16((const char*)Q + (row0 + row) * 512 + ((l5 * 16) ^ ((row & 7) << 4)),
            qa + seg * 1024);
  }
#pragma unroll
  for (int s = 0; s < 4; ++s) {
    int seg = w * 4 + s;
    gload16((const char*)ctxT + (size_t)b * 32768 + seg * 1024 + lane * 16,
            wpB[1] + seg * 1024);
  }
  if (w == 0) gload16((const char*)(ksum + b * 256) + lane * 16, (void*)ksumL);
  __syncthreads();

#pragma unroll
  for (int ii = 0; ii < 2; ++ii) {
    int pp = t + ii * 512;
    int r = pp >> 3, h = pp & 7;
    const unsigned char* qrow = qa + r * 512;
    int swzr = (r & 7) << 4;
    float s = 0.f;
#pragma unroll
    for (int dd = 0; dd < 16; ++dd) {
      unsigned u = *(const unsigned*)(qrow + ((h * 64 + dd * 4) ^ swzr));
      s += __uint_as_float(u << 16) * ksumL[h * 32 + dd * 2] +
           __uint_as_float(u & 0xffff0000u) * ksumL[h * 32 + dd * 2 + 1];
    }
    Dinv_s[r][h] = 1.f / fmaxf(s, 1e-6f);
  }

  const int wrow = w >> 2, cw = w & 3;
  f32x4 sacc[2][4][2];
#pragma unroll
  for (int h2 = 0; h2 < 2; ++h2)
#pragma unroll
    for (int i = 0; i < 4; ++i)
#pragma unroll
      for (int j = 0; j < 2; ++j)
#pragma unroll
        for (int c = 0; c < 4; ++c) sacc[h2][i][j][c] = 0.f;

#pragma unroll
  for (int h2 = 0; h2 < 2; ++h2) {
    int h = 2 * cw + h2;
#pragma unroll
    for (int i = 0; i < 4; ++i) {
      int ra = wrow * 64 + i * 16 + fr;
      short8 af = *(const short8*)(qa + ra * 512 +
                                   ((h * 64 + fq * 16) ^ ((ra & 7) << 4)));
#pragma unroll
      for (int j = 0; j < 2; ++j) {
        int rb = j * 16 + fr;
        short8 bhi = *(const short8*)(wpB[1] + h * 4096 + rb * 64 + fq * 16);
        short8 blo = *(const short8*)(wpB[1] + h * 4096 + 2048 + rb * 64 + fq * 16);
        sacc[h2][i][j] = __builtin_amdgcn_mfma_f32_16x16x32_bf16(
            af, bhi, sacc[h2][i][j], 0, 0, 0);
        sacc[h2][i][j] = __builtin_amdgcn_mfma_f32_16x16x32_bf16(
            af, blo, sacc[h2][i][j], 0, 0, 0);
      }
    }
  }
  __syncthreads();

#pragma unroll
  for (int h2 = 0; h2 < 2; ++h2) {
    int h = 2 * cw + h2;
#pragma unroll
    for (int i = 0; i < 4; ++i)
#pragma unroll
      for (int j = 0; j < 2; ++j)
#pragma unroll
        for (int reg = 0; reg < 4; ++reg) {
          int r = wrow * 64 + i * 16 + fq * 4 + reg;
          int c = h * 32 + j * 16 + fr;
          float v = sacc[h2][i][j][reg] * Dinv_s[r][h];
          *(unsigned short*)(qa + r * 512 + ((2 * c) ^ ((r & 7) << 4))) = f2bf(v);
        }
  }

  for (int q = 0; q < 4; ++q) {
    unsigned char* wbuf = wpB[q & 1];
    unsigned char* scr = wpB[(q & 1) ^ 1];
#pragma unroll
    for (int s = 0; s < 4; ++s) {
      int seg = w * 4 + s;
      int rowl = seg * 2 + rpar;
      gload16((const char*)wpb + (size_t)(q * 64 + rowl) * 512 +
                  ((l5 * 16) ^ ((rowl & 7) << 4)),
              wbuf + seg * 1024);
    }
    __syncthreads();

    f32x4 oacc[4];
#pragma unroll
    for (int j = 0; j < 4; ++j)
#pragma unroll
      for (int c = 0; c < 4; ++c) oacc[j][c] = 0.f;
    const int ra = w * 16 + fr;
    const int sra = (ra & 7) << 4;
#pragma unroll
    for (int kk = 0; kk < 8; ++kk) {
      short8 af = *(const short8*)(qa + ra * 512 + ((kk * 64 + fq * 16) ^ sra));
#pragma unroll
      for (int j = 0; j < 4; ++j) {
        int rb = j * 16 + fr;
        short8 bf8 = *(const short8*)(wbuf + rb * 512 +
                                      ((kk * 64 + fq * 16) ^ ((rb & 7) << 4)));
        oacc[j] = __builtin_amdgcn_mfma_f32_16x16x32_bf16(af, bf8, oacc[j], 0, 0, 0);
      }
    }
    unsigned char* ws4 = scr + w * 4096;
#pragma unroll
    for (int j = 0; j < 4; ++j) {
      float bj = bias[q * 64 + j * 16 + fr];
#pragma unroll
      for (int reg = 0; reg < 4; ++reg) {
        int ri = fq * 4 + reg;
        int cb = (j * 16 + fr) * 4;
        *(float*)(ws4 + ri * 256 + (cb ^ ((ri & 7) << 4))) = oacc[j][reg] + bj;
      }
    }
#pragma unroll
    for (int c = 0; c < 4; ++c) {
      int ri = lane >> 2;
      int cb = (lane & 3) * 16 + c * 64;
      uint4 u = *(const uint4*)(ws4 + ri * 256 + (cb ^ ((ri & 7) << 4)));
      *(uint4*)((char*)(out + (row0 + w * 16 + ri) * 256 + q * 64) + cb) = u;
    }
    __syncthreads();
  }
}

// ---------------------------------------------------------------------------
extern "C" void kernel_launch(void* const* d_in, const int* in_sizes, int n_in,
                              void* d_out, int out_size, void* d_ws, size_t ws_size,
                              hipStream_t stream) {
  const float* x = (const float*)d_in[0];
  const float* Wq = (const float*)d_in[1];
  const float* Wkv = (const float*)d_in[2];
  const float* Wproj = (const float*)d_in[3];
  const float* bproj = (const float*)d_in[4];
  float* out = (float*)d_out;

  char* ws = (char*)d_ws;
  unsigned short* Q = (unsigned short*)(ws);                  // 67,108,864
  unsigned short* wcat = (unsigned short*)(ws + 67108864);    // 393,216
  unsigned short* wpb = (unsigned short*)(ws + 67502080);     // 131,072
  float* pctx = (float*)(ws + 67633152);                      // 67,108,864
  float* pksum = (float*)(ws + 134742016);                    // 2,097,152
  unsigned short* ctxT = (unsigned short*)(ws + 136839168);   // 262,144
  float* ksum = (float*)(ws + 137101312);                     // 8,192

  prep_w<<<1024, 256, 0, stream>>>(Wq, Wkv, Wproj, wcat, wpb);
  qkv_ctx<<<2048, 256, 0, stream>>>(x, wcat, Q, pctx, pksum);
  ctx_final2<<<64, 256, 0, stream>>>(pctx, pksum, ctxT, ksum);
  attn_proj<<<1024, 512, 0, stream>>>(Q, ctxT, ksum, wpb, bproj, out);
}

// Round 12
// 197.511 us; speedup vs baseline: 2.7028x; 1.2654x over previous
//
#include <hip/hip_runtime.h>
#include <hip/hip_bf16.h>
#include <cstdint>
#include <cstddef>

typedef __attribute__((ext_vector_type(8))) short short8;
typedef __attribute__((ext_vector_type(4))) float f32x4;

#define DEVI static __device__ __forceinline__

DEVI unsigned short f2bf(float f) {
  unsigned u = __float_as_uint(f);
  unsigned r = u + 0x7fffu + ((u >> 16) & 1u);
  return (unsigned short)(r >> 16);
}
DEVI float bf2f(unsigned short s) {
  return __uint_as_float(((unsigned)s) << 16);
}
DEVI unsigned pack2(float a, float b) {
  return (unsigned)f2bf(a) | ((unsigned)f2bf(b) << 16);
}

DEVI void gload16(const void* g, void* l) {
  __builtin_amdgcn_global_load_lds(
      (__attribute__((address_space(1))) void*)g,
      (__attribute__((address_space(3))) void*)l, 16, 0, 0);
}

// ---------------------------------------------------------------------------
// prep_w: Wq/Wkv -> wcat bf16 [768][256], Wproj -> wpb bf16 [256][256]
// ---------------------------------------------------------------------------
__global__ __launch_bounds__(256) void prep_w(
    const float* __restrict__ Wq, const float* __restrict__ Wkv,
    const float* __restrict__ Wp, unsigned short* __restrict__ wcat,
    unsigned short* __restrict__ wpb) {
  int i = blockIdx.x * 256 + threadIdx.x;
  if (i < 196608) {
    float v = (i < 65536) ? Wq[i] : Wkv[i - 65536];
    wcat[i] = f2bf(v);
  } else {
    int j = i - 196608;
    wpb[j] = f2bf(Wp[j]);
  }
}

// ---------------------------------------------------------------------------
// qkv_ctx v3: x fragments loaded DIRECT global->registers (xfc[8], 32 VGPR,
// read once, reused by all 24 slivers). No xa LDS tile at all.
// 2048 blocks x 256 thr (4 waves), one 64-row panel each. 24 W-slivers
// (32 rows), ping-pong gload_lds:
//  s0..7   Q: swapped mfma(wf,xfc) -> lane holds 4 consecutive Q-cols;
//          wave-private 80B-stride bounce, b64 writes, b128 read, 64B stores.
//  s8+2h   K head h: elu -> kT[32d][64n] transposed, packed b64 writes.
//  s9+2h   V head h: -> vT packed; ctx+ksum MFMA per head (ones-operand).
// LDS 40KB: wb0/wb1 16K, kT/vT 4K  -> 3 blocks/CU.
// ---------------------------------------------------------------------------
__global__ __launch_bounds__(256) void qkv_ctx(
    const float* __restrict__ x, const unsigned short* __restrict__ wcat,
    unsigned short* __restrict__ Q, float* __restrict__ pctx,
    float* __restrict__ pksum) {
  const int t = threadIdx.x;
  const int lane = t & 63, w = t >> 6;  // 4 waves
  const int p = blockIdx.x;             // 2048 panels of 64 rows
  const size_t row0 = (size_t)p * 64;
  const int fr = lane & 15, fq = lane >> 4;

  __shared__ __align__(16) unsigned char smem[40960];
  unsigned char* const wb0 = smem;           // 16KB [32][512B]
  unsigned char* const wb1 = smem + 16384;   // 16KB
  unsigned char* const kT = smem + 32768;    // 4KB [32 d][128B] ^((d&7)<<4)
  unsigned char* const vT = smem + 36864;    // 4KB

  const short ob = (short)0x3F80;
  const short8 ones = {ob, ob, ob, ob, ob, ob, ob, ob};

  // ---- x fragments direct to registers: row = w*16+fr, k = ks*32+fq*8.. ----
  short8 xfc[8];
  {
    const float* xr = x + (row0 + w * 16 + fr) * 256;
#pragma unroll
    for (int ks = 0; ks < 8; ++ks) {
      float4 a = *(const float4*)(xr + ks * 32 + fq * 8);
      float4 b2 = *(const float4*)(xr + ks * 32 + fq * 8 + 4);
      union { unsigned u[4]; short8 s; } cv;
      cv.u[0] = pack2(a.x, a.y);
      cv.u[1] = pack2(a.z, a.w);
      cv.u[2] = pack2(b2.x, b2.y);
      cv.u[3] = pack2(b2.z, b2.w);
      xfc[ks] = cv.s;
    }
  }

  const int segr = lane >> 5;
  const int segc = (lane & 31) * 16;
  auto stage_w = [&](unsigned char* buf, int s) {
    int wr0 = (s < 8) ? s * 32
                      : (((s & 1) == 0) ? 256 + ((s - 8) >> 1) * 32
                                        : 512 + ((s - 8) >> 1) * 32);
#pragma unroll
    for (int i = 0; i < 4; ++i) {
      int seg = w * 4 + i;
      int rloc = seg * 2 + segr;
      gload16((const char*)wcat + (size_t)(wr0 + rloc) * 512 +
                  (segc ^ ((rloc & 7) << 4)),
              buf + seg * 1024);
    }
  };

  auto ctx_head = [&](int h) {
    const int dp = w >> 1, ep = w & 1;
    f32x4 cacc = {0.f, 0.f, 0.f, 0.f};
    f32x4 sacc = {0.f, 0.f, 0.f, 0.f};
    const int rka = dp * 16 + fr;
    const int rkb = ep * 16 + fr;
#pragma unroll
    for (int ks = 0; ks < 2; ++ks) {
      short8 ak = *(const short8*)(kT + rka * 128 +
                                   ((ks * 64 + fq * 16) ^ ((rka & 7) << 4)));
      short8 bv = *(const short8*)(vT + rkb * 128 +
                                   ((ks * 64 + fq * 16) ^ ((rkb & 7) << 4)));
      cacc = __builtin_amdgcn_mfma_f32_16x16x32_bf16(ak, bv, cacc, 0, 0, 0);
      if (ep == 0)
        sacc = __builtin_amdgcn_mfma_f32_16x16x32_bf16(ak, ones, sacc, 0, 0, 0);
    }
    float* pc = pctx + ((size_t)(p * 8 + h)) * 1024;
#pragma unroll
    for (int reg = 0; reg < 4; ++reg) {
      int d = dp * 16 + fq * 4 + reg;
      int e = ep * 16 + fr;
      pc[d * 32 + e] = cacc[reg];
    }
    if (ep == 0 && fr == 0) {
#pragma unroll
      for (int reg = 0; reg < 4; ++reg) {
        int d = dp * 16 + fq * 4 + reg;
        pksum[((size_t)(p * 8 + h)) * 32 + d] = sacc[reg];
      }
    }
  };

  stage_w(wb0, 0);
  __syncthreads();

  unsigned char* const bb = kT + w * 1280;  // wave-private bounce [16][80B]

  for (int s = 0; s < 24; ++s) {
    if (s >= 10 && (s & 1) == 0) ctx_head((s - 10) >> 1);
    if (s < 23) stage_w(((s & 1) == 0) ? wb1 : wb0, s + 1);

    const unsigned char* wbuf = ((s & 1) == 0) ? wb0 : wb1;

    if (s < 8) {
      // ---- Q sliver: swapped operands -> lane has 4 consecutive Q-cols ----
      f32x4 acc[2] = {{0.f, 0.f, 0.f, 0.f}, {0.f, 0.f, 0.f, 0.f}};
#pragma unroll
      for (int ks = 0; ks < 8; ++ks) {
#pragma unroll
        for (int j = 0; j < 2; ++j) {
          int rb = j * 16 + fr;
          short8 wf = *(const short8*)(wbuf + rb * 512 +
                                       ((ks * 64 + fq * 16) ^ ((rb & 7) << 4)));
          acc[j] = __builtin_amdgcn_mfma_f32_16x16x32_bf16(wf, xfc[ks], acc[j],
                                                           0, 0, 0);
        }
      }
#pragma unroll
      for (int j = 0; j < 2; ++j) {
        float v0 = acc[j][0], v1 = acc[j][1], v2 = acc[j][2], v3 = acc[j][3];
        v0 = (v0 > 0.f) ? (v0 + 1.f) : __expf(v0);
        v1 = (v1 > 0.f) ? (v1 + 1.f) : __expf(v1);
        v2 = (v2 > 0.f) ? (v2 + 1.f) : __expf(v2);
        v3 = (v3 > 0.f) ? (v3 + 1.f) : __expf(v3);
        uint2 pk;
        pk.x = pack2(v0, v1);
        pk.y = pack2(v2, v3);
        *(uint2*)(bb + fr * 80 + j * 32 + fq * 8) = pk;
      }
      {
        int rowq = lane >> 2, c4 = lane & 3;
        uint4 u = *(const uint4*)(bb + rowq * 80 + c4 * 16);
        *(uint4*)((char*)Q + (row0 + w * 16 + rowq) * 512 + s * 64 + c4 * 16) = u;
      }
    } else {
      // ---- K/V sliver: packed b64 transposed writes ----
      f32x4 acc[2] = {{0.f, 0.f, 0.f, 0.f}, {0.f, 0.f, 0.f, 0.f}};
#pragma unroll
      for (int ks = 0; ks < 8; ++ks) {
#pragma unroll
        for (int j = 0; j < 2; ++j) {
          int rb = j * 16 + fr;
          short8 wf = *(const short8*)(wbuf + rb * 512 +
                                       ((ks * 64 + fq * 16) ^ ((rb & 7) << 4)));
          acc[j] = __builtin_amdgcn_mfma_f32_16x16x32_bf16(xfc[ks], wf, acc[j],
                                                           0, 0, 0);
        }
      }
      __syncthreads();  // previous ctx_head reads done before kT/vT overwrite

      const bool isK = ((s & 1) == 0);
      unsigned char* dstT = isK ? kT : vT;
#pragma unroll
      for (int j = 0; j < 2; ++j) {
        int d = j * 16 + fr;
        float v0 = acc[j][0], v1 = acc[j][1], v2 = acc[j][2], v3 = acc[j][3];
        if (isK) {
          v0 = (v0 > 0.f) ? (v0 + 1.f) : __expf(v0);
          v1 = (v1 > 0.f) ? (v1 + 1.f) : __expf(v1);
          v2 = (v2 > 0.f) ? (v2 + 1.f) : __expf(v2);
          v3 = (v3 > 0.f) ? (v3 + 1.f) : __expf(v3);
        }
        uint2 pk;
        pk.x = pack2(v0, v1);
        pk.y = pack2(v2, v3);
        *(uint2*)(dstT + d * 128 + ((w * 32 + fq * 8) ^ ((d & 7) << 4))) = pk;
      }
    }
    __syncthreads();
  }
  ctx_head(7);
}

// ---------------------------------------------------------------------------
// ctx_final2: reduce 256 panel-partials per (b,h) -> ctxT bf16 hi/lo + ksum
// ---------------------------------------------------------------------------
__global__ __launch_bounds__(256) void ctx_final2(
    const float* __restrict__ pctx, const float* __restrict__ pksum,
    unsigned short* __restrict__ ctxT, float* __restrict__ ksum) {
  int bh = blockIdx.x;
  int b = bh >> 3, h = bh & 7;
  int t = threadIdx.x;
  int d = t >> 3, e4 = (t & 7) * 4;
  float s[4] = {0.f, 0.f, 0.f, 0.f};
  for (int pp = 0; pp < 256; ++pp) {
    const float* q = pctx + ((size_t)((b * 256 + pp) * 8 + h)) * 1024 + d * 32 + e4;
    s[0] += q[0]; s[1] += q[1]; s[2] += q[2]; s[3] += q[3];
  }
  unsigned short* cc = ctxT + (size_t)bh * 2048;
#pragma unroll
  for (int e2 = 0; e2 < 4; ++e2) {
    int e = e4 + e2;
    unsigned short hi = f2bf(s[e2]);
    float lo = s[e2] - bf2f(hi);
    cc[e * 32 + d] = hi;
    cc[1024 + e * 32 + d] = f2bf(lo);
  }
  __shared__ float ksp[8][32];
  int d2 = t & 31, ch = t >> 5;
  float ss = 0.f;
  for (int pp = ch; pp < 256; pp += 8)
    ss += pksum[((size_t)((b * 256 + pp) * 8 + h)) * 32 + d2];
  ksp[ch][d2] = ss;
  __syncthreads();
  if (t < 32) {
    float r = 0.f;
#pragma unroll
    for (int c = 0; c < 8; ++c) r += ksp[c][t];
    ksum[bh * 32 + t] = r;
  }
}

// ---------------------------------------------------------------------------
// attn_proj v2: 2048 blocks (64-row panels), 512 thr (8 waves), 68.6KB LDS
// -> 2 blocks/CU.  ctx via coalesced global loads (L3-resident).
//  1. stage qa [64][512B] swz + ksumL
//  2. Dinv[r][h]: 512 pairs, 1/thread
//  3. S = q @ ctx (hi+lo MFMA, ctx B-frags from global, 1KB coalesced)
//  4. writeback attn*Dinv -> qa (A-layout)
//  5. out = attn @ Wp^T + bias: 8 stages of 32 out-cols, ping-pong 16KB,
//     direct f32 stores (64B row-segments)
// ---------------------------------------------------------------------------
__global__ __launch_bounds__(512) void attn_proj(
    const unsigned short* __restrict__ Q,
    const unsigned short* __restrict__ ctxT,
    const float* __restrict__ ksum,
    const unsigned short* __restrict__ wpb,
    const float* __restrict__ bias,
    float* __restrict__ out) {
  const int t = threadIdx.x;
  const int lane = t & 63, w = t >> 6;  // 8 waves
  const int panel = blockIdx.x;         // 2048
  const int b = panel >> 8;
  const size_t row0 = (size_t)panel * 64;
  const int fr = lane & 15, fq = lane >> 4;

  __shared__ __align__(16) unsigned char qa[32768];      // [64][512B] swz
  __shared__ __align__(16) unsigned char wpS[2][16384];  // ping-pong W stages
  __shared__ float ksumL[256];
  __shared__ float Dinv_s[64][8];

  // ---- stage qa (32 segs, 4/wave) + ksumL ----
#pragma unroll
  for (int s = 0; s < 4; ++s) {
    int seg = w * 4 + s;
    int row = seg * 2 + (lane >> 5);
    gload16((const char*)Q + (row0 + row) * 512 +
                (((lane & 31) * 16) ^ ((row & 7) << 4)),
            qa + seg * 1024);
  }
  if (w == 0) gload16((const char*)(ksum + b * 256) + lane * 16, (void*)ksumL);
  __syncthreads();

  // ---- Dinv: 512 (row,head) pairs, 1 per thread ----
  {
    int r = t >> 3, h = t & 7;
    const unsigned char* qrow = qa + r * 512;
    int swzr = (r & 7) << 4;
    float s = 0.f;
#pragma unroll
    for (int dd = 0; dd < 16; ++dd) {
      unsigned u = *(const unsigned*)(qrow + ((h * 64 + dd * 4) ^ swzr));
      s += __uint_as_float(u << 16) * ksumL[h * 32 + dd * 2] +
           __uint_as_float(u & 0xffff0000u) * ksumL[h * 32 + dd * 2 + 1];
    }
    Dinv_s[r][h] = 1.f / fmaxf(s, 1e-6f);
  }

  // ---- S = q @ ctx: wave = (rg = w>>2) x (hg = w&3); 16 MFMA ----
  const int rg = w >> 2, hg = w & 3;
  f32x4 sacc[2][2][2];  // [h2][i][j]
#pragma unroll
  for (int h2 = 0; h2 < 2; ++h2)
#pragma unroll
    for (int i = 0; i < 2; ++i)
#pragma unroll
      for (int j = 0; j < 2; ++j)
#pragma unroll
        for (int c = 0; c < 4; ++c) sacc[h2][i][j][c] = 0.f;

#pragma unroll
  for (int h2 = 0; h2 < 2; ++h2) {
    int h = hg * 2 + h2;
    const char* cbh = (const char*)ctxT + ((size_t)(b * 8 + h)) * 4096;
    short8 bhi[2], blo[2];
#pragma unroll
    for (int j = 0; j < 2; ++j) {
      int e = j * 16 + fr;
      bhi[j] = *(const short8*)(cbh + e * 64 + fq * 16);
      blo[j] = *(const short8*)(cbh + 2048 + e * 64 + fq * 16);
    }
#pragma unroll
    for (int i = 0; i < 2; ++i) {
      int ra = rg * 32 + i * 16 + fr;
      short8 af = *(const short8*)(qa + ra * 512 +
                                   ((h * 64 + fq * 16) ^ ((ra & 7) << 4)));
#pragma unroll
      for (int j = 0; j < 2; ++j) {
        sacc[h2][i][j] = __builtin_amdgcn_mfma_f32_16x16x32_bf16(
            af, bhi[j], sacc[h2][i][j], 0, 0, 0);
        sacc[h2][i][j] = __builtin_amdgcn_mfma_f32_16x16x32_bf16(
            af, blo[j], sacc[h2][i][j], 0, 0, 0);
      }
    }
  }
  __syncthreads();  // Dinv_s visible; all qa reads done

  // ---- writeback attn*Dinv -> qa ----
#pragma unroll
  for (int h2 = 0; h2 < 2; ++h2) {
    int h = hg * 2 + h2;
#pragma unroll
    for (int i = 0; i < 2; ++i)
#pragma unroll
      for (int j = 0; j < 2; ++j)
#pragma unroll
        for (int reg = 0; reg < 4; ++reg) {
          int r = rg * 32 + i * 16 + fq * 4 + reg;
          int e = j * 16 + fr;
          float v = sacc[h2][i][j][reg] * Dinv_s[r][h];
          *(unsigned short*)(qa + r * 512 +
                             ((h * 64 + e * 2) ^ ((r & 7) << 4))) = f2bf(v);
        }
  }

  // ---- out-proj: 8 stages of 32 out-cols, ping-pong ----
  auto stage_wp = [&](int q, unsigned char* buf) {
#pragma unroll
    for (int i = 0; i < 2; ++i) {
      int seg = w * 2 + i;
      int rloc = seg * 2 + (lane >> 5);
      gload16((const char*)wpb + (size_t)(q * 32 + rloc) * 512 +
                  (((lane & 31) * 16) ^ ((rloc & 7) << 4)),
              buf + seg * 1024);
    }
  };
  stage_wp(0, wpS[0]);
  __syncthreads();  // attn in qa visible; wpS[0] ready

  const int rw = w >> 1, cw = w & 1;
  const int ra2 = rw * 16 + fr;
  const int sra2 = (ra2 & 7) << 4;
  for (int q = 0; q < 8; ++q) {
    if (q < 7) stage_wp(q + 1, wpS[(q + 1) & 1]);
    const unsigned char* wbuf = wpS[q & 1];
    f32x4 oacc = {0.f, 0.f, 0.f, 0.f};
#pragma unroll
    for (int ks = 0; ks < 8; ++ks) {
      short8 af = *(const short8*)(qa + ra2 * 512 + ((ks * 64 + fq * 16) ^ sra2));
      int rb = cw * 16 + fr;
      short8 wf = *(const short8*)(wbuf + rb * 512 +
                                   ((ks * 64 + fq * 16) ^ ((rb & 7) << 4)));
      oacc = __builtin_amdgcn_mfma_f32_16x16x32_bf16(af, wf, oacc, 0, 0, 0);
    }
    float bj = bias[q * 32 + cw * 16 + fr];
    float* orow = out + row0 * 256 + (size_t)(rw * 16 + fq * 4) * 256 +
                  q * 32 + cw * 16 + fr;
#pragma unroll
    for (int reg = 0; reg < 4; ++reg) orow[reg * 256] = oacc[reg] + bj;
    __syncthreads();
  }
}

// ---------------------------------------------------------------------------
extern "C" void kernel_launch(void* const* d_in, const int* in_sizes, int n_in,
                              void* d_out, int out_size, void* d_ws, size_t ws_size,
                              hipStream_t stream) {
  const float* x = (const float*)d_in[0];
  const float* Wq = (const float*)d_in[1];
  const float* Wkv = (const float*)d_in[2];
  const float* Wproj = (const float*)d_in[3];
  const float* bproj = (const float*)d_in[4];
  float* out = (float*)d_out;

  char* ws = (char*)d_ws;
  unsigned short* Q = (unsigned short*)(ws);                  // 67,108,864
  unsigned short* wcat = (unsigned short*)(ws + 67108864);    // 393,216
  unsigned short* wpb = (unsigned short*)(ws + 67502080);     // 131,072
  float* pctx = (float*)(ws + 67633152);                      // 67,108,864
  float* pksum = (float*)(ws + 134742016);                    // 2,097,152
  unsigned short* ctxT = (unsigned short*)(ws + 136839168);   // 262,144
  float* ksum = (float*)(ws + 137101312);                     // 8,192

  prep_w<<<1024, 256, 0, stream>>>(Wq, Wkv, Wproj, wcat, wpb);
  qkv_ctx<<<2048, 256, 0, stream>>>(x, wcat, Q, pctx, pksum);
  ctx_final2<<<64, 256, 0, stream>>>(pctx, pksum, ctxT, ksum);
  attn_proj<<<2048, 512, 0, stream>>>(Q, ctxT, ksum, wpb, bproj, out);
}

// Round 13
// 176.986 us; speedup vs baseline: 3.0162x; 1.1160x over previous
//
#include <hip/hip_runtime.h>
#include <hip/hip_bf16.h>
#include <cstdint>
#include <cstddef>

typedef __attribute__((ext_vector_type(8))) short short8;
typedef __attribute__((ext_vector_type(4))) float f32x4;

#define DEVI static __device__ __forceinline__

DEVI unsigned short f2bf(float f) {
  unsigned u = __float_as_uint(f);
  unsigned r = u + 0x7fffu + ((u >> 16) & 1u);
  return (unsigned short)(r >> 16);
}
DEVI float bf2f(unsigned short s) {
  return __uint_as_float(((unsigned)s) << 16);
}
DEVI unsigned pack2(float a, float b) {
  return (unsigned)f2bf(a) | ((unsigned)f2bf(b) << 16);
}

DEVI void gload16(const void* g, void* l) {
  __builtin_amdgcn_global_load_lds(
      (__attribute__((address_space(1))) void*)g,
      (__attribute__((address_space(3))) void*)l, 16, 0, 0);
}

// ---------------------------------------------------------------------------
// prep_w: Wq/Wkv -> wcat bf16 [768][256], Wproj -> wpb bf16 [256][256]
// ---------------------------------------------------------------------------
__global__ __launch_bounds__(256) void prep_w(
    const float* __restrict__ Wq, const float* __restrict__ Wkv,
    const float* __restrict__ Wp, unsigned short* __restrict__ wcat,
    unsigned short* __restrict__ wpb) {
  int i = blockIdx.x * 256 + threadIdx.x;
  if (i < 196608) {
    float v = (i < 65536) ? Wq[i] : Wkv[i - 65536];
    wcat[i] = f2bf(v);
  } else {
    int j = i - 196608;
    wpb[j] = f2bf(Wp[j]);
  }
}

// ---------------------------------------------------------------------------
// qkv_ctx v4: 1024 blocks x 512 thr (8 waves = 4 row-groups x 2 col-groups),
// 128 rows/block. xfc[2][8] per wave (rows wr*32+i*16+fr). 24 W-slivers
// (32 rows) ping-pong gload_lds; each wave reads only its 16-row B-half
// (8 b128/sliver -> 2 MFMA per LDS read).
//  s0..7   Q: swapped mfma(wf,xfc[i]); wave-private 40B-stride bounce ->
//          32B-coalesced stores (wc pair completes 64B lines).
//  s8+2h   K head h: elu -> kT[32d][128n] packed b64; ctx_head(h-1) overlap.
//  s9+2h   V head h: -> vT; barrier; (ctx_head(h) in next K sliver).
// ctx_head: 4 ks MFMA + ones-MFMA ksum; writes pctx[blk][h][32][32]+pksum.
// LDS 48KB: wb0/wb1 16K, kT/vT 8K. VGPR cap 128 (launch_bounds 512,4).
// ---------------------------------------------------------------------------
__global__ __launch_bounds__(512, 4) void qkv_ctx(
    const float* __restrict__ x, const unsigned short* __restrict__ wcat,
    unsigned short* __restrict__ Q, float* __restrict__ pctx,
    float* __restrict__ pksum) {
  const int t = threadIdx.x;
  const int lane = t & 63, w = t >> 6;  // 8 waves
  const int wr = w >> 1, wc = w & 1;    // 4 x 2
  const int blk = blockIdx.x;           // 1024 blocks of 128 rows
  const size_t row0 = (size_t)blk * 128;
  const int fr = lane & 15, fq = lane >> 4;

  __shared__ __align__(16) unsigned char smem[49152];
  unsigned char* const wb0 = smem;           // 16KB [32][512B]
  unsigned char* const wb1 = smem + 16384;   // 16KB
  unsigned char* const kT = smem + 32768;    // 8KB [32 d][256B] ^((d&7)<<4)
  unsigned char* const vT = smem + 40960;    // 8KB

  const short ob = (short)0x3F80;
  const short8 ones = {ob, ob, ob, ob, ob, ob, ob, ob};

  // ---- x fragments direct to registers: rows wr*32 + i*16 + fr ----
  short8 xfc[2][8];
#pragma unroll
  for (int i = 0; i < 2; ++i) {
    const float* xr = x + (row0 + wr * 32 + i * 16 + fr) * 256;
#pragma unroll
    for (int ks = 0; ks < 8; ++ks) {
      float4 a = *(const float4*)(xr + ks * 32 + fq * 8);
      float4 b2 = *(const float4*)(xr + ks * 32 + fq * 8 + 4);
      union { unsigned u[4]; short8 s; } cv;
      cv.u[0] = pack2(a.x, a.y);
      cv.u[1] = pack2(a.z, a.w);
      cv.u[2] = pack2(b2.x, b2.y);
      cv.u[3] = pack2(b2.z, b2.w);
      xfc[i][ks] = cv.s;
    }
  }

  const int segr = lane >> 5;
  const int segc = (lane & 31) * 16;
  auto stage_w = [&](unsigned char* buf, int s) {
    int wr0 = (s < 8) ? s * 32
                      : (((s & 1) == 0) ? 256 + ((s - 8) >> 1) * 32
                                        : 512 + ((s - 8) >> 1) * 32);
#pragma unroll
    for (int i = 0; i < 2; ++i) {
      int seg = w * 2 + i;
      int rloc = seg * 2 + segr;
      gload16((const char*)wcat + (size_t)(wr0 + rloc) * 512 +
                  (segc ^ ((rloc & 7) << 4)),
              buf + seg * 1024);
    }
  };

  // ctx: waves 0-3 only (dp = w>>1, ep = w&1); 4 ks steps over 128 n
  auto ctx_head = [&](int h) {
    if (w < 4) {
      const int dp = w >> 1, ep = w & 1;
      f32x4 cacc = {0.f, 0.f, 0.f, 0.f};
      f32x4 sacc = {0.f, 0.f, 0.f, 0.f};
      const int rka = dp * 16 + fr;
      const int rkb = ep * 16 + fr;
#pragma unroll
      for (int ks = 0; ks < 4; ++ks) {
        short8 ak = *(const short8*)(kT + rka * 256 +
                                     ((ks * 64 + fq * 16) ^ ((rka & 7) << 4)));
        short8 bv = *(const short8*)(vT + rkb * 256 +
                                     ((ks * 64 + fq * 16) ^ ((rkb & 7) << 4)));
        cacc = __builtin_amdgcn_mfma_f32_16x16x32_bf16(ak, bv, cacc, 0, 0, 0);
        if (ep == 0)
          sacc = __builtin_amdgcn_mfma_f32_16x16x32_bf16(ak, ones, sacc, 0, 0, 0);
      }
      float* pc = pctx + ((size_t)(blk * 8 + h)) * 1024;
#pragma unroll
      for (int reg = 0; reg < 4; ++reg) {
        int d = dp * 16 + fq * 4 + reg;
        int e = ep * 16 + fr;
        pc[d * 32 + e] = cacc[reg];
      }
      if (ep == 0 && fr == 0) {
#pragma unroll
        for (int reg = 0; reg < 4; ++reg) {
          int d = dp * 16 + fq * 4 + reg;
          pksum[((size_t)(blk * 8 + h)) * 32 + d] = sacc[reg];
        }
      }
    }
  };

  stage_w(wb0, 0);
  __syncthreads();

  unsigned char* const bb = kT + w * 1280;  // wave-private bounce [32][40B]

  // ================= Q phase: slivers 0..7 =================
#pragma unroll
  for (int s = 0; s < 8; ++s) {
    stage_w((s & 1) ? wb0 : wb1, s + 1);
    const unsigned char* wbuf = (s & 1) ? wb1 : wb0;

    f32x4 acc[2] = {{0.f, 0.f, 0.f, 0.f}, {0.f, 0.f, 0.f, 0.f}};
    const int rb = wc * 16 + fr;
    const int swb = (rb & 7) << 4;
#pragma unroll
    for (int ks = 0; ks < 8; ++ks) {
      short8 wf = *(const short8*)(wbuf + rb * 512 + ((ks * 64 + fq * 16) ^ swb));
      acc[0] = __builtin_amdgcn_mfma_f32_16x16x32_bf16(wf, xfc[0][ks], acc[0], 0, 0, 0);
      acc[1] = __builtin_amdgcn_mfma_f32_16x16x32_bf16(wf, xfc[1][ks], acc[1], 0, 0, 0);
    }
    // lane holds Q[x-row wr*32+i*16+fr][col s*32 + wc*16 + fq*4 + 0..3]
#pragma unroll
    for (int i = 0; i < 2; ++i) {
      float v0 = acc[i][0], v1 = acc[i][1], v2 = acc[i][2], v3 = acc[i][3];
      v0 = (v0 > 0.f) ? (v0 + 1.f) : __expf(v0);
      v1 = (v1 > 0.f) ? (v1 + 1.f) : __expf(v1);
      v2 = (v2 > 0.f) ? (v2 + 1.f) : __expf(v2);
      v3 = (v3 > 0.f) ? (v3 + 1.f) : __expf(v3);
      uint2 pk;
      pk.x = pack2(v0, v1);
      pk.y = pack2(v2, v3);
      *(uint2*)(bb + (i * 16 + fr) * 40 + fq * 8) = pk;
    }
    {
      int rowq = lane >> 1, ch = lane & 1;
      uint4 u = *(const uint4*)(bb + rowq * 40 + ch * 16);
      *(uint4*)((char*)Q + (row0 + wr * 32 + rowq) * 512 + s * 64 + wc * 32 +
                ch * 16) = u;
    }
    __syncthreads();
  }

  // ================= K/V phase: heads 0..7 =================
#pragma unroll
  for (int h = 0; h < 8; ++h) {
    const int sk = 8 + 2 * h;
    // ---- K sliver (wb0) ----
    stage_w(wb1, sk + 1);  // V head h
    f32x4 kacc[2] = {{0.f, 0.f, 0.f, 0.f}, {0.f, 0.f, 0.f, 0.f}};
    {
      const int rb = wc * 16 + fr;
      const int swb = (rb & 7) << 4;
#pragma unroll
      for (int ks = 0; ks < 8; ++ks) {
        short8 wf = *(const short8*)(wb0 + rb * 512 + ((ks * 64 + fq * 16) ^ swb));
        kacc[0] = __builtin_amdgcn_mfma_f32_16x16x32_bf16(xfc[0][ks], wf, kacc[0], 0, 0, 0);
        kacc[1] = __builtin_amdgcn_mfma_f32_16x16x32_bf16(xfc[1][ks], wf, kacc[1], 0, 0, 0);
      }
    }
    if (h > 0) ctx_head(h - 1);  // reads kT/vT of head h-1
    __syncthreads();  // ctx reads done; V staged; wb0 reads done

    // kT write: d = wc*16+fr, n = wr*32 + i*16 + fq*4 + 0..3 (elu)
#pragma unroll
    for (int i = 0; i < 2; ++i) {
      int d = wc * 16 + fr;
      float v0 = kacc[i][0], v1 = kacc[i][1], v2 = kacc[i][2], v3 = kacc[i][3];
      v0 = (v0 > 0.f) ? (v0 + 1.f) : __expf(v0);
      v1 = (v1 > 0.f) ? (v1 + 1.f) : __expf(v1);
      v2 = (v2 > 0.f) ? (v2 + 1.f) : __expf(v2);
      v3 = (v3 > 0.f) ? (v3 + 1.f) : __expf(v3);
      uint2 pk;
      pk.x = pack2(v0, v1);
      pk.y = pack2(v2, v3);
      int nb = wr * 64 + i * 32 + fq * 8;  // byte offset = n*2
      *(uint2*)(kT + d * 256 + (nb ^ ((d & 7) << 4))) = pk;
    }

    // ---- V sliver (wb1) ----
    if (h < 7) stage_w(wb0, sk + 2);  // K head h+1
    f32x4 vacc[2] = {{0.f, 0.f, 0.f, 0.f}, {0.f, 0.f, 0.f, 0.f}};
    {
      const int rb = wc * 16 + fr;
      const int swb = (rb & 7) << 4;
#pragma unroll
      for (int ks = 0; ks < 8; ++ks) {
        short8 wf = *(const short8*)(wb1 + rb * 512 + ((ks * 64 + fq * 16) ^ swb));
        vacc[0] = __builtin_amdgcn_mfma_f32_16x16x32_bf16(xfc[0][ks], wf, vacc[0], 0, 0, 0);
        vacc[1] = __builtin_amdgcn_mfma_f32_16x16x32_bf16(xfc[1][ks], wf, vacc[1], 0, 0, 0);
      }
    }
    // vT write (prev ctx reads of vT completed at the K-barrier)
#pragma unroll
    for (int i = 0; i < 2; ++i) {
      int e = wc * 16 + fr;
      uint2 pk;
      pk.x = pack2(vacc[i][0], vacc[i][1]);
      pk.y = pack2(vacc[i][2], vacc[i][3]);
      int nb = wr * 64 + i * 32 + fq * 8;
      *(uint2*)(vT + e * 256 + (nb ^ ((e & 7) << 4))) = pk;
    }
    __syncthreads();  // kT+vT visible; stages complete
  }
  ctx_head(7);
}

// ---------------------------------------------------------------------------
// ctx_final2: reduce 128 block-partials per (b,h) -> ctxT bf16 hi/lo + ksum
// ---------------------------------------------------------------------------
__global__ __launch_bounds__(256) void ctx_final2(
    const float* __restrict__ pctx, const float* __restrict__ pksum,
    unsigned short* __restrict__ ctxT, float* __restrict__ ksum) {
  int bh = blockIdx.x;
  int b = bh >> 3, h = bh & 7;
  int t = threadIdx.x;
  int d = t >> 3, e4 = (t & 7) * 4;
  float s[4] = {0.f, 0.f, 0.f, 0.f};
  for (int pp = 0; pp < 128; ++pp) {
    const float* q = pctx + ((size_t)((b * 128 + pp) * 8 + h)) * 1024 + d * 32 + e4;
    s[0] += q[0]; s[1] += q[1]; s[2] += q[2]; s[3] += q[3];
  }
  unsigned short* cc = ctxT + (size_t)bh * 2048;
#pragma unroll
  for (int e2 = 0; e2 < 4; ++e2) {
    int e = e4 + e2;
    unsigned short hi = f2bf(s[e2]);
    float lo = s[e2] - bf2f(hi);
    cc[e * 32 + d] = hi;
    cc[1024 + e * 32 + d] = f2bf(lo);
  }
  __shared__ float ksp[8][32];
  int d2 = t & 31, ch = t >> 5;
  float ss = 0.f;
  for (int pp = ch; pp < 128; pp += 8)
    ss += pksum[((size_t)((b * 128 + pp) * 8 + h)) * 32 + d2];
  ksp[ch][d2] = ss;
  __syncthreads();
  if (t < 32) {
    float r = 0.f;
#pragma unroll
    for (int c = 0; c < 8; ++c) r += ksp[c][t];
    ksum[bh * 32 + t] = r;
  }
}

// ---------------------------------------------------------------------------
// attn_proj (round-12 proven, unchanged): 2048 blocks (64-row panels),
// 512 thr, 68.6KB LDS -> 2 blocks/CU.
// ---------------------------------------------------------------------------
__global__ __launch_bounds__(512) void attn_proj(
    const unsigned short* __restrict__ Q,
    const unsigned short* __restrict__ ctxT,
    const float* __restrict__ ksum,
    const unsigned short* __restrict__ wpb,
    const float* __restrict__ bias,
    float* __restrict__ out) {
  const int t = threadIdx.x;
  const int lane = t & 63, w = t >> 6;  // 8 waves
  const int panel = blockIdx.x;         // 2048
  const int b = panel >> 8;
  const size_t row0 = (size_t)panel * 64;
  const int fr = lane & 15, fq = lane >> 4;

  __shared__ __align__(16) unsigned char qa[32768];      // [64][512B] swz
  __shared__ __align__(16) unsigned char wpS[2][16384];  // ping-pong W stages
  __shared__ float ksumL[256];
  __shared__ float Dinv_s[64][8];

#pragma unroll
  for (int s = 0; s < 4; ++s) {
    int seg = w * 4 + s;
    int row = seg * 2 + (lane >> 5);
    gload16((const char*)Q + (row0 + row) * 512 +
                (((lane & 31) * 16) ^ ((row & 7) << 4)),
            qa + seg * 1024);
  }
  if (w == 0) gload16((const char*)(ksum + b * 256) + lane * 16, (void*)ksumL);
  __syncthreads();

  {
    int r = t >> 3, h = t & 7;
    const unsigned char* qrow = qa + r * 512;
    int swzr = (r & 7) << 4;
    float s = 0.f;
#pragma unroll
    for (int dd = 0; dd < 16; ++dd) {
      unsigned u = *(const unsigned*)(qrow + ((h * 64 + dd * 4) ^ swzr));
      s += __uint_as_float(u << 16) * ksumL[h * 32 + dd * 2] +
           __uint_as_float(u & 0xffff0000u) * ksumL[h * 32 + dd * 2 + 1];
    }
    Dinv_s[r][h] = 1.f / fmaxf(s, 1e-6f);
  }

  const int rg = w >> 2, hg = w & 3;
  f32x4 sacc[2][2][2];
#pragma unroll
  for (int h2 = 0; h2 < 2; ++h2)
#pragma unroll
    for (int i = 0; i < 2; ++i)
#pragma unroll
      for (int j = 0; j < 2; ++j)
#pragma unroll
        for (int c = 0; c < 4; ++c) sacc[h2][i][j][c] = 0.f;

#pragma unroll
  for (int h2 = 0; h2 < 2; ++h2) {
    int h = hg * 2 + h2;
    const char* cbh = (const char*)ctxT + ((size_t)(b * 8 + h)) * 4096;
    short8 bhi[2], blo[2];
#pragma unroll
    for (int j = 0; j < 2; ++j) {
      int e = j * 16 + fr;
      bhi[j] = *(const short8*)(cbh + e * 64 + fq * 16);
      blo[j] = *(const short8*)(cbh + 2048 + e * 64 + fq * 16);
    }
#pragma unroll
    for (int i = 0; i < 2; ++i) {
      int ra = rg * 32 + i * 16 + fr;
      short8 af = *(const short8*)(qa + ra * 512 +
                                   ((h * 64 + fq * 16) ^ ((ra & 7) << 4)));
#pragma unroll
      for (int j = 0; j < 2; ++j) {
        sacc[h2][i][j] = __builtin_amdgcn_mfma_f32_16x16x32_bf16(
            af, bhi[j], sacc[h2][i][j], 0, 0, 0);
        sacc[h2][i][j] = __builtin_amdgcn_mfma_f32_16x16x32_bf16(
            af, blo[j], sacc[h2][i][j], 0, 0, 0);
      }
    }
  }
  __syncthreads();

#pragma unroll
  for (int h2 = 0; h2 < 2; ++h2) {
    int h = hg * 2 + h2;
#pragma unroll
    for (int i = 0; i < 2; ++i)
#pragma unroll
      for (int j = 0; j < 2; ++j)
#pragma unroll
        for (int reg = 0; reg < 4; ++reg) {
          int r = rg * 32 + i * 16 + fq * 4 + reg;
          int e = j * 16 + fr;
          float v = sacc[h2][i][j][reg] * Dinv_s[r][h];
          *(unsigned short*)(qa + r * 512 +
                             ((h * 64 + e * 2) ^ ((r & 7) << 4))) = f2bf(v);
        }
  }

  auto stage_wp = [&](int q, unsigned char* buf) {
#pragma unroll
    for (int i = 0; i < 2; ++i) {
      int seg = w * 2 + i;
      int rloc = seg * 2 + (lane >> 5);
      gload16((const char*)wpb + (size_t)(q * 32 + rloc) * 512 +
                  (((lane & 31) * 16) ^ ((rloc & 7) << 4)),
              buf + seg * 1024);
    }
  };
  stage_wp(0, wpS[0]);
  __syncthreads();

  const int rw = w >> 1, cw = w & 1;
  const int ra2 = rw * 16 + fr;
  const int sra2 = (ra2 & 7) << 4;
  for (int q = 0; q < 8; ++q) {
    if (q < 7) stage_wp(q + 1, wpS[(q + 1) & 1]);
    const unsigned char* wbuf = wpS[q & 1];
    f32x4 oacc = {0.f, 0.f, 0.f, 0.f};
#pragma unroll
    for (int ks = 0; ks < 8; ++ks) {
      short8 af = *(const short8*)(qa + ra2 * 512 + ((ks * 64 + fq * 16) ^ sra2));
      int rb = cw * 16 + fr;
      short8 wf = *(const short8*)(wbuf + rb * 512 +
                                   ((ks * 64 + fq * 16) ^ ((rb & 7) << 4)));
      oacc = __builtin_amdgcn_mfma_f32_16x16x32_bf16(af, wf, oacc, 0, 0, 0);
    }
    float bj = bias[q * 32 + cw * 16 + fr];
    float* orow = out + row0 * 256 + (size_t)(rw * 16 + fq * 4) * 256 +
                  q * 32 + cw * 16 + fr;
#pragma unroll
    for (int reg = 0; reg < 4; ++reg) orow[reg * 256] = oacc[reg] + bj;
    __syncthreads();
  }
}

// ---------------------------------------------------------------------------
extern "C" void kernel_launch(void* const* d_in, const int* in_sizes, int n_in,
                              void* d_out, int out_size, void* d_ws, size_t ws_size,
                              hipStream_t stream) {
  const float* x = (const float*)d_in[0];
  const float* Wq = (const float*)d_in[1];
  const float* Wkv = (const float*)d_in[2];
  const float* Wproj = (const float*)d_in[3];
  const float* bproj = (const float*)d_in[4];
  float* out = (float*)d_out;

  char* ws = (char*)d_ws;
  unsigned short* Q = (unsigned short*)(ws);                  // 67,108,864
  unsigned short* wcat = (unsigned short*)(ws + 67108864);    // 393,216
  unsigned short* wpb = (unsigned short*)(ws + 67502080);     // 131,072
  float* pctx = (float*)(ws + 67633152);                      // 33,554,432
  float* pksum = (float*)(ws + 101187584);                    // 1,048,576
  unsigned short* ctxT = (unsigned short*)(ws + 102236160);   // 262,144
  float* ksum = (float*)(ws + 102498304);                     // 8,192

  prep_w<<<1024, 256, 0, stream>>>(Wq, Wkv, Wproj, wcat, wpb);
  qkv_ctx<<<1024, 512, 0, stream>>>(x, wcat, Q, pctx, pksum);
  ctx_final2<<<64, 256, 0, stream>>>(pctx, pksum, ctxT, ksum);
  attn_proj<<<2048, 512, 0, stream>>>(Q, ctxT, ksum, wpb, bproj, out);
}

// Round 15
// 174.780 us; speedup vs baseline: 3.0543x; 1.0126x over previous
//
#include <hip/hip_runtime.h>
#include <hip/hip_bf16.h>
#include <cstdint>
#include <cstddef>

typedef __attribute__((ext_vector_type(8))) short short8;
typedef __attribute__((ext_vector_type(4))) float f32x4;

#define DEVI static __device__ __forceinline__

DEVI unsigned short f2bf(float f) {
  unsigned u = __float_as_uint(f);
  unsigned r = u + 0x7fffu + ((u >> 16) & 1u);
  return (unsigned short)(r >> 16);
}
DEVI float bf2f(unsigned short s) {
  return __uint_as_float(((unsigned)s) << 16);
}
DEVI unsigned pack2(float a, float b) {
  return (unsigned)f2bf(a) | ((unsigned)f2bf(b) << 16);
}

DEVI void gload16(const void* g, void* l) {
  __builtin_amdgcn_global_load_lds(
      (__attribute__((address_space(1))) void*)g,
      (__attribute__((address_space(3))) void*)l, 16, 0, 0);
}

// ---------------------------------------------------------------------------
// prep_w: Wq/Wkv -> wcat bf16 [768][256], Wproj -> wpb bf16 [256][256]
// ---------------------------------------------------------------------------
__global__ __launch_bounds__(256) void prep_w(
    const float* __restrict__ Wq, const float* __restrict__ Wkv,
    const float* __restrict__ Wp, unsigned short* __restrict__ wcat,
    unsigned short* __restrict__ wpb) {
  int i = blockIdx.x * 256 + threadIdx.x;
  if (i < 196608) {
    float v = (i < 65536) ? Wq[i] : Wkv[i - 65536];
    wcat[i] = f2bf(v);
  } else {
    int j = i - 196608;
    wpb[j] = f2bf(Wp[j]);
  }
}

// ---------------------------------------------------------------------------
// qkv_ctx v4.2 = round-13 kernel + 48B-stride bounce (16B-aligned b128 reads).
// 1024 blocks x 512 thr (8 waves = 4 row-groups x 2 col-groups), 128 rows.
// xfc[2][8] per wave. 24 W-slivers (32 rows) ping-pong gload_lds; each wave
// reads only its 16-row B-half (2 MFMA per LDS read).
//  s0..7   Q: swapped mfma(wf,xfc[i]); wave-private 48B-stride bounce ->
//          32B-coalesced stores.
//  s8+2h   K head h: elu -> kT[32d][256B] packed b64; ctx_head(h-1) overlap.
//  s9+2h   V head h: -> vT; barrier; (ctx_head(h) in next K sliver).
// ctx_head: 4 ks MFMA + ones-MFMA ksum; pctx[blk][h][32][32]+pksum.
// LDS 48KB. VGPR cap 128 (launch_bounds 512,4).
// ---------------------------------------------------------------------------
__global__ __launch_bounds__(512, 4) void qkv_ctx(
    const float* __restrict__ x, const unsigned short* __restrict__ wcat,
    unsigned short* __restrict__ Q, float* __restrict__ pctx,
    float* __restrict__ pksum) {
  const int t = threadIdx.x;
  const int lane = t & 63, w = t >> 6;  // 8 waves
  const int wr = w >> 1, wc = w & 1;    // 4 x 2
  const int blk = blockIdx.x;           // 1024 blocks of 128 rows
  const size_t row0 = (size_t)blk * 128;
  const int fr = lane & 15, fq = lane >> 4;

  __shared__ __align__(16) unsigned char smem[49152];
  unsigned char* const wb0 = smem;           // 16KB [32][512B]
  unsigned char* const wb1 = smem + 16384;   // 16KB
  unsigned char* const kT = smem + 32768;    // 8KB [32 d][256B] ^((d&7)<<4)
  unsigned char* const vT = smem + 40960;    // 8KB

  const short ob = (short)0x3F80;
  const short8 ones = {ob, ob, ob, ob, ob, ob, ob, ob};

  // ---- x fragments direct to registers: rows wr*32 + i*16 + fr ----
  short8 xfc[2][8];
#pragma unroll
  for (int i = 0; i < 2; ++i) {
    const float* xr = x + (row0 + wr * 32 + i * 16 + fr) * 256;
#pragma unroll
    for (int ks = 0; ks < 8; ++ks) {
      float4 a = *(const float4*)(xr + ks * 32 + fq * 8);
      float4 b2 = *(const float4*)(xr + ks * 32 + fq * 8 + 4);
      union { unsigned u[4]; short8 s; } cv;
      cv.u[0] = pack2(a.x, a.y);
      cv.u[1] = pack2(a.z, a.w);
      cv.u[2] = pack2(b2.x, b2.y);
      cv.u[3] = pack2(b2.z, b2.w);
      xfc[i][ks] = cv.s;
    }
  }

  const int segr = lane >> 5;
  const int segc = (lane & 31) * 16;
  auto stage_w = [&](unsigned char* buf, int s) {
    int wr0 = (s < 8) ? s * 32
                      : (((s & 1) == 0) ? 256 + ((s - 8) >> 1) * 32
                                        : 512 + ((s - 8) >> 1) * 32);
#pragma unroll
    for (int i = 0; i < 2; ++i) {
      int seg = w * 2 + i;
      int rloc = seg * 2 + segr;
      gload16((const char*)wcat + (size_t)(wr0 + rloc) * 512 +
                  (segc ^ ((rloc & 7) << 4)),
              buf + seg * 1024);
    }
  };

  // ctx: waves 0-3 only (dp = w>>1, ep = w&1); 4 ks steps over 128 n
  auto ctx_head = [&](int h) {
    if (w < 4) {
      const int dp = w >> 1, ep = w & 1;
      f32x4 cacc = {0.f, 0.f, 0.f, 0.f};
      f32x4 sacc = {0.f, 0.f, 0.f, 0.f};
      const int rka = dp * 16 + fr;
      const int rkb = ep * 16 + fr;
#pragma unroll
      for (int ks = 0; ks < 4; ++ks) {
        short8 ak = *(const short8*)(kT + rka * 256 +
                                     ((ks * 64 + fq * 16) ^ ((rka & 7) << 4)));
        short8 bv = *(const short8*)(vT + rkb * 256 +
                                     ((ks * 64 + fq * 16) ^ ((rkb & 7) << 4)));
        cacc = __builtin_amdgcn_mfma_f32_16x16x32_bf16(ak, bv, cacc, 0, 0, 0);
        if (ep == 0)
          sacc = __builtin_amdgcn_mfma_f32_16x16x32_bf16(ak, ones, sacc, 0, 0, 0);
      }
      float* pc = pctx + ((size_t)(blk * 8 + h)) * 1024;
#pragma unroll
      for (int reg = 0; reg < 4; ++reg) {
        int d = dp * 16 + fq * 4 + reg;
        int e = ep * 16 + fr;
        pc[d * 32 + e] = cacc[reg];
      }
      if (ep == 0 && fr == 0) {
#pragma unroll
        for (int reg = 0; reg < 4; ++reg) {
          int d = dp * 16 + fq * 4 + reg;
          pksum[((size_t)(blk * 8 + h)) * 32 + d] = sacc[reg];
        }
      }
    }
  };

  stage_w(wb0, 0);
  __syncthreads();

  unsigned char* const bb = kT + w * 1536;  // wave-private bounce [32][48B]

  // ================= Q phase: slivers 0..7 =================
#pragma unroll
  for (int s = 0; s < 8; ++s) {
    stage_w((s & 1) ? wb0 : wb1, s + 1);
    const unsigned char* wbuf = (s & 1) ? wb1 : wb0;

    f32x4 acc[2] = {{0.f, 0.f, 0.f, 0.f}, {0.f, 0.f, 0.f, 0.f}};
    const int rb = wc * 16 + fr;
    const int swb = (rb & 7) << 4;
#pragma unroll
    for (int ks = 0; ks < 8; ++ks) {
      short8 wf = *(const short8*)(wbuf + rb * 512 + ((ks * 64 + fq * 16) ^ swb));
      acc[0] = __builtin_amdgcn_mfma_f32_16x16x32_bf16(wf, xfc[0][ks], acc[0], 0, 0, 0);
      acc[1] = __builtin_amdgcn_mfma_f32_16x16x32_bf16(wf, xfc[1][ks], acc[1], 0, 0, 0);
    }
    // lane holds Q[x-row wr*32+i*16+fr][col s*32 + wc*16 + fq*4 + 0..3]
#pragma unroll
    for (int i = 0; i < 2; ++i) {
      float v0 = acc[i][0], v1 = acc[i][1], v2 = acc[i][2], v3 = acc[i][3];
      v0 = (v0 > 0.f) ? (v0 + 1.f) : __expf(v0);
      v1 = (v1 > 0.f) ? (v1 + 1.f) : __expf(v1);
      v2 = (v2 > 0.f) ? (v2 + 1.f) : __expf(v2);
      v3 = (v3 > 0.f) ? (v3 + 1.f) : __expf(v3);
      uint2 pk;
      pk.x = pack2(v0, v1);
      pk.y = pack2(v2, v3);
      *(uint2*)(bb + (i * 16 + fr) * 48 + fq * 8) = pk;
    }
    {
      int rowq = lane >> 1, ch = lane & 1;
      uint4 u = *(const uint4*)(bb + rowq * 48 + ch * 16);
      *(uint4*)((char*)Q + (row0 + wr * 32 + rowq) * 512 + s * 64 + wc * 32 +
                ch * 16) = u;
    }
    __syncthreads();
  }

  // ================= K/V phase: heads 0..7 =================
#pragma unroll
  for (int h = 0; h < 8; ++h) {
    const int sk = 8 + 2 * h;
    // ---- K sliver (wb0) ----
    stage_w(wb1, sk + 1);  // V head h
    f32x4 kacc[2] = {{0.f, 0.f, 0.f, 0.f}, {0.f, 0.f, 0.f, 0.f}};
    {
      const int rb = wc * 16 + fr;
      const int swb = (rb & 7) << 4;
#pragma unroll
      for (int ks = 0; ks < 8; ++ks) {
        short8 wf = *(const short8*)(wb0 + rb * 512 + ((ks * 64 + fq * 16) ^ swb));
        kacc[0] = __builtin_amdgcn_mfma_f32_16x16x32_bf16(xfc[0][ks], wf, kacc[0], 0, 0, 0);
        kacc[1] = __builtin_amdgcn_mfma_f32_16x16x32_bf16(xfc[1][ks], wf, kacc[1], 0, 0, 0);
      }
    }
    if (h > 0) ctx_head(h - 1);  // reads kT/vT of head h-1
    __syncthreads();  // ctx reads done; V staged; wb0 reads done

    // kT write: d = wc*16+fr, n = wr*32 + i*16 + fq*4 + 0..3 (elu)
#pragma unroll
    for (int i = 0; i < 2; ++i) {
      int d = wc * 16 + fr;
      float v0 = kacc[i][0], v1 = kacc[i][1], v2 = kacc[i][2], v3 = kacc[i][3];
      v0 = (v0 > 0.f) ? (v0 + 1.f) : __expf(v0);
      v1 = (v1 > 0.f) ? (v1 + 1.f) : __expf(v1);
      v2 = (v2 > 0.f) ? (v2 + 1.f) : __expf(v2);
      v3 = (v3 > 0.f) ? (v3 + 1.f) : __expf(v3);
      uint2 pk;
      pk.x = pack2(v0, v1);
      pk.y = pack2(v2, v3);
      int nb = wr * 64 + i * 32 + fq * 8;  // byte offset = n*2
      *(uint2*)(kT + d * 256 + (nb ^ ((d & 7) << 4))) = pk;
    }

    // ---- V sliver (wb1) ----
    if (h < 7) stage_w(wb0, sk + 2);  // K head h+1
    f32x4 vacc[2] = {{0.f, 0.f, 0.f, 0.f}, {0.f, 0.f, 0.f, 0.f}};
    {
      const int rb = wc * 16 + fr;
      const int swb = (rb & 7) << 4;
#pragma unroll
      for (int ks = 0; ks < 8; ++ks) {
        short8 wf = *(const short8*)(wb1 + rb * 512 + ((ks * 64 + fq * 16) ^ swb));
        vacc[0] = __builtin_amdgcn_mfma_f32_16x16x32_bf16(xfc[0][ks], wf, vacc[0], 0, 0, 0);
        vacc[1] = __builtin_amdgcn_mfma_f32_16x16x32_bf16(xfc[1][ks], wf, vacc[1], 0, 0, 0);
      }
    }
    // vT write (prev ctx reads of vT completed at the K-barrier)
#pragma unroll
    for (int i = 0; i < 2; ++i) {
      int e = wc * 16 + fr;
      uint2 pk;
      pk.x = pack2(vacc[i][0], vacc[i][1]);
      pk.y = pack2(vacc[i][2], vacc[i][3]);
      int nb = wr * 64 + i * 32 + fq * 8;
      *(uint2*)(vT + e * 256 + (nb ^ ((e & 7) << 4))) = pk;
    }
    __syncthreads();  // kT+vT visible; stages complete
  }
  ctx_head(7);
}

// ---------------------------------------------------------------------------
// ctx_final2: reduce 128 block-partials per (b,h) -> ctxT bf16 hi/lo + ksum
// ---------------------------------------------------------------------------
__global__ __launch_bounds__(256) void ctx_final2(
    const float* __restrict__ pctx, const float* __restrict__ pksum,
    unsigned short* __restrict__ ctxT, float* __restrict__ ksum) {
  int bh = blockIdx.x;
  int b = bh >> 3, h = bh & 7;
  int t = threadIdx.x;
  int d = t >> 3, e4 = (t & 7) * 4;
  float s[4] = {0.f, 0.f, 0.f, 0.f};
  for (int pp = 0; pp < 128; ++pp) {
    const float* q = pctx + ((size_t)((b * 128 + pp) * 8 + h)) * 1024 + d * 32 + e4;
    s[0] += q[0]; s[1] += q[1]; s[2] += q[2]; s[3] += q[3];
  }
  unsigned short* cc = ctxT + (size_t)bh * 2048;
#pragma unroll
  for (int e2 = 0; e2 < 4; ++e2) {
    int e = e4 + e2;
    unsigned short hi = f2bf(s[e2]);
    float lo = s[e2] - bf2f(hi);
    cc[e * 32 + d] = hi;
    cc[1024 + e * 32 + d] = f2bf(lo);
  }
  __shared__ float ksp[8][32];
  int d2 = t & 31, ch = t >> 5;
  float ss = 0.f;
  for (int pp = ch; pp < 128; pp += 8)
    ss += pksum[((size_t)((b * 128 + pp) * 8 + h)) * 32 + d2];
  ksp[ch][d2] = ss;
  __syncthreads();
  if (t < 32) {
    float r = 0.f;
#pragma unroll
    for (int c = 0; c < 8; ++c) r += ksp[c][t];
    ksum[bh * 32 + t] = r;
  }
}

// ---------------------------------------------------------------------------
// attn_proj (round-12/13 proven, unchanged): 2048 blocks (64-row panels),
// 512 thr, 68.6KB LDS -> 2 blocks/CU.
// ---------------------------------------------------------------------------
__global__ __launch_bounds__(512) void attn_proj(
    const unsigned short* __restrict__ Q,
    const unsigned short* __restrict__ ctxT,
    const float* __restrict__ ksum,
    const unsigned short* __restrict__ wpb,
    const float* __restrict__ bias,
    float* __restrict__ out) {
  const int t = threadIdx.x;
  const int lane = t & 63, w = t >> 6;  // 8 waves
  const int panel = blockIdx.x;         // 2048
  const int b = panel >> 8;
  const size_t row0 = (size_t)panel * 64;
  const int fr = lane & 15, fq = lane >> 4;

  __shared__ __align__(16) unsigned char qa[32768];      // [64][512B] swz
  __shared__ __align__(16) unsigned char wpS[2][16384];  // ping-pong W stages
  __shared__ float ksumL[256];
  __shared__ float Dinv_s[64][8];

#pragma unroll
  for (int s = 0; s < 4; ++s) {
    int seg = w * 4 + s;
    int row = seg * 2 + (lane >> 5);
    gload16((const char*)Q + (row0 + row) * 512 +
                (((lane & 31) * 16) ^ ((row & 7) << 4)),
            qa + seg * 1024);
  }
  if (w == 0) gload16((const char*)(ksum + b * 256) + lane * 16, (void*)ksumL);
  __syncthreads();

  {
    int r = t >> 3, h = t & 7;
    const unsigned char* qrow = qa + r * 512;
    int swzr = (r & 7) << 4;
    float s = 0.f;
#pragma unroll
    for (int dd = 0; dd < 16; ++dd) {
      unsigned u = *(const unsigned*)(qrow + ((h * 64 + dd * 4) ^ swzr));
      s += __uint_as_float(u << 16) * ksumL[h * 32 + dd * 2] +
           __uint_as_float(u & 0xffff0000u) * ksumL[h * 32 + dd * 2 + 1];
    }
    Dinv_s[r][h] = 1.f / fmaxf(s, 1e-6f);
  }

  const int rg = w >> 2, hg = w & 3;
  f32x4 sacc[2][2][2];
#pragma unroll
  for (int h2 = 0; h2 < 2; ++h2)
#pragma unroll
    for (int i = 0; i < 2; ++i)
#pragma unroll
      for (int j = 0; j < 2; ++j)
#pragma unroll
        for (int c = 0; c < 4; ++c) sacc[h2][i][j][c] = 0.f;

#pragma unroll
  for (int h2 = 0; h2 < 2; ++h2) {
    int h = hg * 2 + h2;
    const char* cbh = (const char*)ctxT + ((size_t)(b * 8 + h)) * 4096;
    short8 bhi[2], blo[2];
#pragma unroll
    for (int j = 0; j < 2; ++j) {
      int e = j * 16 + fr;
      bhi[j] = *(const short8*)(cbh + e * 64 + fq * 16);
      blo[j] = *(const short8*)(cbh + 2048 + e * 64 + fq * 16);
    }
#pragma unroll
    for (int i = 0; i < 2; ++i) {
      int ra = rg * 32 + i * 16 + fr;
      short8 af = *(const short8*)(qa + ra * 512 +
                                   ((h * 64 + fq * 16) ^ ((ra & 7) << 4)));
#pragma unroll
      for (int j = 0; j < 2; ++j) {
        sacc[h2][i][j] = __builtin_amdgcn_mfma_f32_16x16x32_bf16(
            af, bhi[j], sacc[h2][i][j], 0, 0, 0);
        sacc[h2][i][j] = __builtin_amdgcn_mfma_f32_16x16x32_bf16(
            af, blo[j], sacc[h2][i][j], 0, 0, 0);
      }
    }
  }
  __syncthreads();

#pragma unroll
  for (int h2 = 0; h2 < 2; ++h2) {
    int h = hg * 2 + h2;
#pragma unroll
    for (int i = 0; i < 2; ++i)
#pragma unroll
      for (int j = 0; j < 2; ++j)
#pragma unroll
        for (int reg = 0; reg < 4; ++reg) {
          int r = rg * 32 + i * 16 + fq * 4 + reg;
          int e = j * 16 + fr;
          float v = sacc[h2][i][j][reg] * Dinv_s[r][h];
          *(unsigned short*)(qa + r * 512 +
                             ((h * 64 + e * 2) ^ ((r & 7) << 4))) = f2bf(v);
        }
  }

  auto stage_wp = [&](int q, unsigned char* buf) {
#pragma unroll
    for (int i = 0; i < 2; ++i) {
      int seg = w * 2 + i;
      int rloc = seg * 2 + (lane >> 5);
      gload16((const char*)wpb + (size_t)(q * 32 + rloc) * 512 +
                  (((lane & 31) * 16) ^ ((rloc & 7) << 4)),
              buf + seg * 1024);
    }
  };
  stage_wp(0, wpS[0]);
  __syncthreads();

  const int rw = w >> 1, cw = w & 1;
  const int ra2 = rw * 16 + fr;
  const int sra2 = (ra2 & 7) << 4;
  for (int q = 0; q < 8; ++q) {
    if (q < 7) stage_wp(q + 1, wpS[(q + 1) & 1]);
    const unsigned char* wbuf = wpS[q & 1];
    f32x4 oacc = {0.f, 0.f, 0.f, 0.f};
#pragma unroll
    for (int ks = 0; ks < 8; ++ks) {
      short8 af = *(const short8*)(qa + ra2 * 512 + ((ks * 64 + fq * 16) ^ sra2));
      int rb = cw * 16 + fr;
      short8 wf = *(const short8*)(wbuf + rb * 512 +
                                   ((ks * 64 + fq * 16) ^ ((rb & 7) << 4)));
      oacc = __builtin_amdgcn_mfma_f32_16x16x32_bf16(af, wf, oacc, 0, 0, 0);
    }
    float bj = bias[q * 32 + cw * 16 + fr];
    float* orow = out + row0 * 256 + (size_t)(rw * 16 + fq * 4) * 256 +
                  q * 32 + cw * 16 + fr;
#pragma unroll
    for (int reg = 0; reg < 4; ++reg) orow[reg * 256] = oacc[reg] + bj;
    __syncthreads();
  }
}

// ---------------------------------------------------------------------------
extern "C" void kernel_launch(void* const* d_in, const int* in_sizes, int n_in,
                              void* d_out, int out_size, void* d_ws, size_t ws_size,
                              hipStream_t stream) {
  const float* x = (const float*)d_in[0];
  const float* Wq = (const float*)d_in[1];
  const float* Wkv = (const float*)d_in[2];
  const float* Wproj = (const float*)d_in[3];
  const float* bproj = (const float*)d_in[4];
  float* out = (float*)d_out;

  char* ws = (char*)d_ws;
  unsigned short* Q = (unsigned short*)(ws);                  // 67,108,864
  unsigned short* wcat = (unsigned short*)(ws + 67108864);    // 393,216
  unsigned short* wpb = (unsigned short*)(ws + 67502080);     // 131,072
  float* pctx = (float*)(ws + 67633152);                      // 33,554,432
  float* pksum = (float*)(ws + 101187584);                    // 1,048,576
  unsigned short* ctxT = (unsigned short*)(ws + 102236160);   // 262,144
  float* ksum = (float*)(ws + 102498304);                     // 8,192

  prep_w<<<1024, 256, 0, stream>>>(Wq, Wkv, Wproj, wcat, wpb);
  qkv_ctx<<<1024, 512, 0, stream>>>(x, wcat, Q, pctx, pksum);
  ctx_final2<<<64, 256, 0, stream>>>(pctx, pksum, ctxT, ksum);
  attn_proj<<<2048, 512, 0, stream>>>(Q, ctxT, ksum, wpb, bproj, out);
}

// Round 16
// 174.002 us; speedup vs baseline: 3.0679x; 1.0045x over previous
//
#include <hip/hip_runtime.h>
#include <hip/hip_bf16.h>
#include <cstdint>
#include <cstddef>

typedef __attribute__((ext_vector_type(8))) short short8;
typedef __attribute__((ext_vector_type(4))) float f32x4;

#define DEVI static __device__ __forceinline__

DEVI unsigned short f2bf(float f) {
  unsigned u = __float_as_uint(f);
  unsigned r = u + 0x7fffu + ((u >> 16) & 1u);
  return (unsigned short)(r >> 16);
}
DEVI float bf2f(unsigned short s) {
  return __uint_as_float(((unsigned)s) << 16);
}
DEVI unsigned pack2(float a, float b) {
  return (unsigned)f2bf(a) | ((unsigned)f2bf(b) << 16);
}

DEVI void gload16(const void* g, void* l) {
  __builtin_amdgcn_global_load_lds(
      (__attribute__((address_space(1))) void*)g,
      (__attribute__((address_space(3))) void*)l, 16, 0, 0);
}

// ---------------------------------------------------------------------------
// prep_w: Wq/Wkv -> wcat bf16 [768][256], Wproj -> wpb bf16 [256][256]
// ---------------------------------------------------------------------------
__global__ __launch_bounds__(256) void prep_w(
    const float* __restrict__ Wq, const float* __restrict__ Wkv,
    const float* __restrict__ Wp, unsigned short* __restrict__ wcat,
    unsigned short* __restrict__ wpb) {
  int i = blockIdx.x * 256 + threadIdx.x;
  if (i < 196608) {
    float v = (i < 65536) ? Wq[i] : Wkv[i - 65536];
    wcat[i] = f2bf(v);
  } else {
    int j = i - 196608;
    wpb[j] = f2bf(Wp[j]);
  }
}

// ---------------------------------------------------------------------------
// qkv_ctx v4.3 = round-15 kernel, K/V phase 3->2 barriers/head, ksum on
// waves 4-5 (waves 0-3 do pure ctx).
// 1024 blocks x 512 thr (8 waves = 4 row-groups x 2 col-groups), 128 rows.
// xfc[2][8] per wave. 24 W-slivers (32 rows) ping-pong gload_lds.
//  s0..7   Q: swapped mfma(wf,xfc[i]); 48B-stride bounce -> 32B stores.
//  s8+2h   K head h: elu -> kT[32d][256B] packed b64; ctx/ksum(h-1) overlap.
//  s9+2h   V head h: -> vT (same barrier window).
// LDS 48KB. VGPR cap 128 (launch_bounds 512,4).
// ---------------------------------------------------------------------------
__global__ __launch_bounds__(512, 4) void qkv_ctx(
    const float* __restrict__ x, const unsigned short* __restrict__ wcat,
    unsigned short* __restrict__ Q, float* __restrict__ pctx,
    float* __restrict__ pksum) {
  const int t = threadIdx.x;
  const int lane = t & 63, w = t >> 6;  // 8 waves
  const int wr = w >> 1, wc = w & 1;    // 4 x 2
  const int blk = blockIdx.x;           // 1024 blocks of 128 rows
  const size_t row0 = (size_t)blk * 128;
  const int fr = lane & 15, fq = lane >> 4;

  __shared__ __align__(16) unsigned char smem[49152];
  unsigned char* const wb0 = smem;           // 16KB [32][512B]
  unsigned char* const wb1 = smem + 16384;   // 16KB
  unsigned char* const kT = smem + 32768;    // 8KB [32 d][256B] ^((d&7)<<4)
  unsigned char* const vT = smem + 40960;    // 8KB

  const short ob = (short)0x3F80;
  const short8 ones = {ob, ob, ob, ob, ob, ob, ob, ob};

  // ---- x fragments direct to registers: rows wr*32 + i*16 + fr ----
  short8 xfc[2][8];
#pragma unroll
  for (int i = 0; i < 2; ++i) {
    const float* xr = x + (row0 + wr * 32 + i * 16 + fr) * 256;
#pragma unroll
    for (int ks = 0; ks < 8; ++ks) {
      float4 a = *(const float4*)(xr + ks * 32 + fq * 8);
      float4 b2 = *(const float4*)(xr + ks * 32 + fq * 8 + 4);
      union { unsigned u[4]; short8 s; } cv;
      cv.u[0] = pack2(a.x, a.y);
      cv.u[1] = pack2(a.z, a.w);
      cv.u[2] = pack2(b2.x, b2.y);
      cv.u[3] = pack2(b2.z, b2.w);
      xfc[i][ks] = cv.s;
    }
  }

  const int segr = lane >> 5;
  const int segc = (lane & 31) * 16;
  auto stage_w = [&](unsigned char* buf, int s) {
    int wr0 = (s < 8) ? s * 32
                      : (((s & 1) == 0) ? 256 + ((s - 8) >> 1) * 32
                                        : 512 + ((s - 8) >> 1) * 32);
#pragma unroll
    for (int i = 0; i < 2; ++i) {
      int seg = w * 2 + i;
      int rloc = seg * 2 + segr;
      gload16((const char*)wcat + (size_t)(wr0 + rloc) * 512 +
                  (segc ^ ((rloc & 7) << 4)),
              buf + seg * 1024);
    }
  };

  // ctx: waves 0-3 (dp = w>>1, ep = w&1); 4 ks steps over 128 n
  auto ctx_head = [&](int h) {
    if (w < 4) {
      const int dp = w >> 1, ep = w & 1;
      f32x4 cacc = {0.f, 0.f, 0.f, 0.f};
      const int rka = dp * 16 + fr;
      const int rkb = ep * 16 + fr;
#pragma unroll
      for (int ks = 0; ks < 4; ++ks) {
        short8 ak = *(const short8*)(kT + rka * 256 +
                                     ((ks * 64 + fq * 16) ^ ((rka & 7) << 4)));
        short8 bv = *(const short8*)(vT + rkb * 256 +
                                     ((ks * 64 + fq * 16) ^ ((rkb & 7) << 4)));
        cacc = __builtin_amdgcn_mfma_f32_16x16x32_bf16(ak, bv, cacc, 0, 0, 0);
      }
      float* pc = pctx + ((size_t)(blk * 8 + h)) * 1024;
#pragma unroll
      for (int reg = 0; reg < 4; ++reg) {
        int d = dp * 16 + fq * 4 + reg;
        int e = ep * 16 + fr;
        pc[d * 32 + e] = cacc[reg];
      }
    }
  };

  // ksum: waves 4-5 (dp = w&1), ones-MFMA on kT
  auto ksum_head = [&](int h) {
    if ((w >> 1) == 2) {
      const int dp = w & 1;
      f32x4 sacc = {0.f, 0.f, 0.f, 0.f};
      const int rka = dp * 16 + fr;
#pragma unroll
      for (int ks = 0; ks < 4; ++ks) {
        short8 ak = *(const short8*)(kT + rka * 256 +
                                     ((ks * 64 + fq * 16) ^ ((rka & 7) << 4)));
        sacc = __builtin_amdgcn_mfma_f32_16x16x32_bf16(ak, ones, sacc, 0, 0, 0);
      }
      if (fr == 0) {
#pragma unroll
        for (int reg = 0; reg < 4; ++reg) {
          int d = dp * 16 + fq * 4 + reg;
          pksum[((size_t)(blk * 8 + h)) * 32 + d] = sacc[reg];
        }
      }
    }
  };

  stage_w(wb0, 0);
  __syncthreads();

  unsigned char* const bb = kT + w * 1536;  // wave-private bounce [32][48B]

  // ================= Q phase: slivers 0..7 =================
#pragma unroll
  for (int s = 0; s < 8; ++s) {
    stage_w((s & 1) ? wb0 : wb1, s + 1);
    const unsigned char* wbuf = (s & 1) ? wb1 : wb0;

    f32x4 acc[2] = {{0.f, 0.f, 0.f, 0.f}, {0.f, 0.f, 0.f, 0.f}};
    const int rb = wc * 16 + fr;
    const int swb = (rb & 7) << 4;
#pragma unroll
    for (int ks = 0; ks < 8; ++ks) {
      short8 wf = *(const short8*)(wbuf + rb * 512 + ((ks * 64 + fq * 16) ^ swb));
      acc[0] = __builtin_amdgcn_mfma_f32_16x16x32_bf16(wf, xfc[0][ks], acc[0], 0, 0, 0);
      acc[1] = __builtin_amdgcn_mfma_f32_16x16x32_bf16(wf, xfc[1][ks], acc[1], 0, 0, 0);
    }
    // lane holds Q[x-row wr*32+i*16+fr][col s*32 + wc*16 + fq*4 + 0..3]
#pragma unroll
    for (int i = 0; i < 2; ++i) {
      float v0 = acc[i][0], v1 = acc[i][1], v2 = acc[i][2], v3 = acc[i][3];
      v0 = (v0 > 0.f) ? (v0 + 1.f) : __expf(v0);
      v1 = (v1 > 0.f) ? (v1 + 1.f) : __expf(v1);
      v2 = (v2 > 0.f) ? (v2 + 1.f) : __expf(v2);
      v3 = (v3 > 0.f) ? (v3 + 1.f) : __expf(v3);
      uint2 pk;
      pk.x = pack2(v0, v1);
      pk.y = pack2(v2, v3);
      *(uint2*)(bb + (i * 16 + fr) * 48 + fq * 8) = pk;
    }
    {
      int rowq = lane >> 1, ch = lane & 1;
      uint4 u = *(const uint4*)(bb + rowq * 48 + ch * 16);
      *(uint4*)((char*)Q + (row0 + wr * 32 + rowq) * 512 + s * 64 + wc * 32 +
                ch * 16) = u;
    }
    __syncthreads();
  }

  // ================= K/V phase: heads 0..7 (2 barriers/head) =============
#pragma unroll
  for (int h = 0; h < 8; ++h) {
    const int sk = 8 + 2 * h;
    // ---- K sliver (wb0) ----
    stage_w(wb1, sk + 1);  // V head h
    f32x4 kacc[2] = {{0.f, 0.f, 0.f, 0.f}, {0.f, 0.f, 0.f, 0.f}};
    {
      const int rb = wc * 16 + fr;
      const int swb = (rb & 7) << 4;
#pragma unroll
      for (int ks = 0; ks < 8; ++ks) {
        short8 wf = *(const short8*)(wb0 + rb * 512 + ((ks * 64 + fq * 16) ^ swb));
        kacc[0] = __builtin_amdgcn_mfma_f32_16x16x32_bf16(xfc[0][ks], wf, kacc[0], 0, 0, 0);
        kacc[1] = __builtin_amdgcn_mfma_f32_16x16x32_bf16(xfc[1][ks], wf, kacc[1], 0, 0, 0);
      }
    }
    if (h > 0) {
      ctx_head(h - 1);   // waves 0-3: reads kT/vT of head h-1
      ksum_head(h - 1);  // waves 4-5: reads kT of head h-1
    }
    __syncthreads();  // #1: ctx/ksum reads done; V staged; wb0 reads done

    // kT write: d = wc*16+fr, n = wr*32 + i*16 + fq*4 + 0..3 (elu)
#pragma unroll
    for (int i = 0; i < 2; ++i) {
      int d = wc * 16 + fr;
      float v0 = kacc[i][0], v1 = kacc[i][1], v2 = kacc[i][2], v3 = kacc[i][3];
      v0 = (v0 > 0.f) ? (v0 + 1.f) : __expf(v0);
      v1 = (v1 > 0.f) ? (v1 + 1.f) : __expf(v1);
      v2 = (v2 > 0.f) ? (v2 + 1.f) : __expf(v2);
      v3 = (v3 > 0.f) ? (v3 + 1.f) : __expf(v3);
      uint2 pk;
      pk.x = pack2(v0, v1);
      pk.y = pack2(v2, v3);
      int nb = wr * 64 + i * 32 + fq * 8;  // byte offset = n*2
      *(uint2*)(kT + d * 256 + (nb ^ ((d & 7) << 4))) = pk;
    }

    // ---- V sliver (wb1) ----
    if (h < 7) stage_w(wb0, sk + 2);  // K head h+1
    f32x4 vacc[2] = {{0.f, 0.f, 0.f, 0.f}, {0.f, 0.f, 0.f, 0.f}};
    {
      const int rb = wc * 16 + fr;
      const int swb = (rb & 7) << 4;
#pragma unroll
      for (int ks = 0; ks < 8; ++ks) {
        short8 wf = *(const short8*)(wb1 + rb * 512 + ((ks * 64 + fq * 16) ^ swb));
        vacc[0] = __builtin_amdgcn_mfma_f32_16x16x32_bf16(xfc[0][ks], wf, vacc[0], 0, 0, 0);
        vacc[1] = __builtin_amdgcn_mfma_f32_16x16x32_bf16(xfc[1][ks], wf, vacc[1], 0, 0, 0);
      }
    }
    // vT write: prev readers (ctx_head(h-1)) completed before barrier #1
#pragma unroll
    for (int i = 0; i < 2; ++i) {
      int e = wc * 16 + fr;
      uint2 pk;
      pk.x = pack2(vacc[i][0], vacc[i][1]);
      pk.y = pack2(vacc[i][2], vacc[i][3]);
      int nb = wr * 64 + i * 32 + fq * 8;
      *(uint2*)(vT + e * 256 + (nb ^ ((e & 7) << 4))) = pk;
    }
    __syncthreads();  // #2: kT+vT visible; stages drained
  }
  ctx_head(7);
  ksum_head(7);
}

// ---------------------------------------------------------------------------
// ctx_final2: reduce 128 block-partials per (b,h) -> ctxT bf16 hi/lo + ksum
// ---------------------------------------------------------------------------
__global__ __launch_bounds__(256) void ctx_final2(
    const float* __restrict__ pctx, const float* __restrict__ pksum,
    unsigned short* __restrict__ ctxT, float* __restrict__ ksum) {
  int bh = blockIdx.x;
  int b = bh >> 3, h = bh & 7;
  int t = threadIdx.x;
  int d = t >> 3, e4 = (t & 7) * 4;
  float s[4] = {0.f, 0.f, 0.f, 0.f};
  for (int pp = 0; pp < 128; ++pp) {
    const float* q = pctx + ((size_t)((b * 128 + pp) * 8 + h)) * 1024 + d * 32 + e4;
    s[0] += q[0]; s[1] += q[1]; s[2] += q[2]; s[3] += q[3];
  }
  unsigned short* cc = ctxT + (size_t)bh * 2048;
#pragma unroll
  for (int e2 = 0; e2 < 4; ++e2) {
    int e = e4 + e2;
    unsigned short hi = f2bf(s[e2]);
    float lo = s[e2] - bf2f(hi);
    cc[e * 32 + d] = hi;
    cc[1024 + e * 32 + d] = f2bf(lo);
  }
  __shared__ float ksp[8][32];
  int d2 = t & 31, ch = t >> 5;
  float ss = 0.f;
  for (int pp = ch; pp < 128; pp += 8)
    ss += pksum[((size_t)((b * 128 + pp) * 8 + h)) * 32 + d2];
  ksp[ch][d2] = ss;
  __syncthreads();
  if (t < 32) {
    float r = 0.f;
#pragma unroll
    for (int c = 0; c < 8; ++c) r += ksp[c][t];
    ksum[bh * 32 + t] = r;
  }
}

// ---------------------------------------------------------------------------
// attn_proj (round-12/13 proven, unchanged): 2048 blocks (64-row panels),
// 512 thr, 68.6KB LDS -> 2 blocks/CU.
// ---------------------------------------------------------------------------
__global__ __launch_bounds__(512) void attn_proj(
    const unsigned short* __restrict__ Q,
    const unsigned short* __restrict__ ctxT,
    const float* __restrict__ ksum,
    const unsigned short* __restrict__ wpb,
    const float* __restrict__ bias,
    float* __restrict__ out) {
  const int t = threadIdx.x;
  const int lane = t & 63, w = t >> 6;  // 8 waves
  const int panel = blockIdx.x;         // 2048
  const int b = panel >> 8;
  const size_t row0 = (size_t)panel * 64;
  const int fr = lane & 15, fq = lane >> 4;

  __shared__ __align__(16) unsigned char qa[32768];      // [64][512B] swz
  __shared__ __align__(16) unsigned char wpS[2][16384];  // ping-pong W stages
  __shared__ float ksumL[256];
  __shared__ float Dinv_s[64][8];

#pragma unroll
  for (int s = 0; s < 4; ++s) {
    int seg = w * 4 + s;
    int row = seg * 2 + (lane >> 5);
    gload16((const char*)Q + (row0 + row) * 512 +
                (((lane & 31) * 16) ^ ((row & 7) << 4)),
            qa + seg * 1024);
  }
  if (w == 0) gload16((const char*)(ksum + b * 256) + lane * 16, (void*)ksumL);
  __syncthreads();

  {
    int r = t >> 3, h = t & 7;
    const unsigned char* qrow = qa + r * 512;
    int swzr = (r & 7) << 4;
    float s = 0.f;
#pragma unroll
    for (int dd = 0; dd < 16; ++dd) {
      unsigned u = *(const unsigned*)(qrow + ((h * 64 + dd * 4) ^ swzr));
      s += __uint_as_float(u << 16) * ksumL[h * 32 + dd * 2] +
           __uint_as_float(u & 0xffff0000u) * ksumL[h * 32 + dd * 2 + 1];
    }
    Dinv_s[r][h] = 1.f / fmaxf(s, 1e-6f);
  }

  const int rg = w >> 2, hg = w & 3;
  f32x4 sacc[2][2][2];
#pragma unroll
  for (int h2 = 0; h2 < 2; ++h2)
#pragma unroll
    for (int i = 0; i < 2; ++i)
#pragma unroll
      for (int j = 0; j < 2; ++j)
#pragma unroll
        for (int c = 0; c < 4; ++c) sacc[h2][i][j][c] = 0.f;

#pragma unroll
  for (int h2 = 0; h2 < 2; ++h2) {
    int h = hg * 2 + h2;
    const char* cbh = (const char*)ctxT + ((size_t)(b * 8 + h)) * 4096;
    short8 bhi[2], blo[2];
#pragma unroll
    for (int j = 0; j < 2; ++j) {
      int e = j * 16 + fr;
      bhi[j] = *(const short8*)(cbh + e * 64 + fq * 16);
      blo[j] = *(const short8*)(cbh + 2048 + e * 64 + fq * 16);
    }
#pragma unroll
    for (int i = 0; i < 2; ++i) {
      int ra = rg * 32 + i * 16 + fr;
      short8 af = *(const short8*)(qa + ra * 512 +
                                   ((h * 64 + fq * 16) ^ ((ra & 7) << 4)));
#pragma unroll
      for (int j = 0; j < 2; ++j) {
        sacc[h2][i][j] = __builtin_amdgcn_mfma_f32_16x16x32_bf16(
            af, bhi[j], sacc[h2][i][j], 0, 0, 0);
        sacc[h2][i][j] = __builtin_amdgcn_mfma_f32_16x16x32_bf16(
            af, blo[j], sacc[h2][i][j], 0, 0, 0);
      }
    }
  }
  __syncthreads();

#pragma unroll
  for (int h2 = 0; h2 < 2; ++h2) {
    int h = hg * 2 + h2;
#pragma unroll
    for (int i = 0; i < 2; ++i)
#pragma unroll
      for (int j = 0; j < 2; ++j)
#pragma unroll
        for (int reg = 0; reg < 4; ++reg) {
          int r = rg * 32 + i * 16 + fq * 4 + reg;
          int e = j * 16 + fr;
          float v = sacc[h2][i][j][reg] * Dinv_s[r][h];
          *(unsigned short*)(qa + r * 512 +
                             ((h * 64 + e * 2) ^ ((r & 7) << 4))) = f2bf(v);
        }
  }

  auto stage_wp = [&](int q, unsigned char* buf) {
#pragma unroll
    for (int i = 0; i < 2; ++i) {
      int seg = w * 2 + i;
      int rloc = seg * 2 + (lane >> 5);
      gload16((const char*)wpb + (size_t)(q * 32 + rloc) * 512 +
                  (((lane & 31) * 16) ^ ((rloc & 7) << 4)),
              buf + seg * 1024);
    }
  };
  stage_wp(0, wpS[0]);
  __syncthreads();

  const int rw = w >> 1, cw = w & 1;
  const int ra2 = rw * 16 + fr;
  const int sra2 = (ra2 & 7) << 4;
  for (int q = 0; q < 8; ++q) {
    if (q < 7) stage_wp(q + 1, wpS[(q + 1) & 1]);
    const unsigned char* wbuf = wpS[q & 1];
    f32x4 oacc = {0.f, 0.f, 0.f, 0.f};
#pragma unroll
    for (int ks = 0; ks < 8; ++ks) {
      short8 af = *(const short8*)(qa + ra2 * 512 + ((ks * 64 + fq * 16) ^ sra2));
      int rb = cw * 16 + fr;
      short8 wf = *(const short8*)(wbuf + rb * 512 +
                                   ((ks * 64 + fq * 16) ^ ((rb & 7) << 4)));
      oacc = __builtin_amdgcn_mfma_f32_16x16x32_bf16(af, wf, oacc, 0, 0, 0);
    }
    float bj = bias[q * 32 + cw * 16 + fr];
    float* orow = out + row0 * 256 + (size_t)(rw * 16 + fq * 4) * 256 +
                  q * 32 + cw * 16 + fr;
#pragma unroll
    for (int reg = 0; reg < 4; ++reg) orow[reg * 256] = oacc[reg] + bj;
    __syncthreads();
  }
}

// ---------------------------------------------------------------------------
extern "C" void kernel_launch(void* const* d_in, const int* in_sizes, int n_in,
                              void* d_out, int out_size, void* d_ws, size_t ws_size,
                              hipStream_t stream) {
  const float* x = (const float*)d_in[0];
  const float* Wq = (const float*)d_in[1];
  const float* Wkv = (const float*)d_in[2];
  const float* Wproj = (const float*)d_in[3];
  const float* bproj = (const float*)d_in[4];
  float* out = (float*)d_out;

  char* ws = (char*)d_ws;
  unsigned short* Q = (unsigned short*)(ws);                  // 67,108,864
  unsigned short* wcat = (unsigned short*)(ws + 67108864);    // 393,216
  unsigned short* wpb = (unsigned short*)(ws + 67502080);     // 131,072
  float* pctx = (float*)(ws + 67633152);                      // 33,554,432
  float* pksum = (float*)(ws + 101187584);                    // 1,048,576
  unsigned short* ctxT = (unsigned short*)(ws + 102236160);   // 262,144
  float* ksum = (float*)(ws + 102498304);                     // 8,192

  prep_w<<<1024, 256, 0, stream>>>(Wq, Wkv, Wproj, wcat, wpb);
  qkv_ctx<<<1024, 512, 0, stream>>>(x, wcat, Q, pctx, pksum);
  ctx_final2<<<64, 256, 0, stream>>>(pctx, pksum, ctxT, ksum);
  attn_proj<<<2048, 512, 0, stream>>>(Q, ctxT, ksum, wpb, bproj, out);
}